// Round 4
// baseline (5624.596 us; speedup 1.0000x reference)
//
#include <hip/hip_runtime.h>

typedef unsigned short u16;

__device__ __forceinline__ float bf2f(u16 u) {
  return __uint_as_float(((unsigned)u) << 16);
}
__device__ __forceinline__ u16 f2bf(float f) {
  unsigned u = __float_as_uint(f);
  u += 0x7fffu + ((u >> 16) & 1u);  // RNE (no NaNs in this workload)
  return (u16)(u >> 16);
}

// ---------------------------------------------------------------------------
// Constants: B=128, N=500. Stage A/B rows = 64000. Stage C rows padded to
// 1024/batch = 131072 so 64-row tiles never straddle a batch.
// External buffers (d_in, d_out) are FP32. Intermediates in ws are bf16.
// ---------------------------------------------------------------------------
#define M_AB 64000
#define M_C 131072

// ws layout (bytes), peak ~150.6 MB:
// arena A @ 0          (49,152,000): feat(512K) -> l2(32.77M) -> l4 -> l6(49.15M)
// arena B @ 49,152,000 (100,663,296): l1(8.19M) -> l3(32.77M) -> l5(49.15M) -> l7(100.66M)
#define OFF_ARENA_B 49152000u
#define OFF_IDX1 149815296u   // 128x500  int
#define OFF_IDX2 150071296u   // 128x1000 int

// ---------------------------------------------------------------------------
// feat = [sigmoid(x@cW^T+cb), x]  (64000 x 4, bf16)
// ---------------------------------------------------------------------------
__global__ void feat_kernel(const float* __restrict__ x,
                            const float* __restrict__ cW,
                            const float* __restrict__ cb,
                            u16* __restrict__ feat) {
  int i = blockIdx.x * 256 + threadIdx.x;
  if (i >= M_AB) return;
  float x0 = x[i * 3], x1 = x[i * 3 + 1], x2 = x[i * 3 + 2];
  float z = x0 * cW[0] + x1 * cW[1] + x2 * cW[2] + cb[0];
  float conf = 1.0f / (1.0f + expf(-z));
  feat[i * 4 + 0] = f2bf(conf);
  feat[i * 4 + 1] = f2bf(x0);
  feat[i * 4 + 2] = f2bf(x1);
  feat[i * 4 + 3] = f2bf(x2);
}

// ---------------------------------------------------------------------------
// Farthest point sampling. One wave per (batch, which-fps). Exact fp32 math
// (explicit _rn ops, np summation order ((dx2+dy2)+dz2)), first-max
// tie-break = np.argmax.
// ---------------------------------------------------------------------------
__global__ __launch_bounds__(64) void fps_kernel(
    const float* __restrict__ x, const int* __restrict__ init1,
    const int* __restrict__ init2, int* __restrict__ idx1,
    int* __restrict__ idx2) {
  int bb = blockIdx.x;  // 0..255
  int b = bb & 127;
  bool second = bb >= 128;
  int npoint = second ? 1000 : 500;
  int* out = second ? (idx2 + b * 1000) : (idx1 + b * 500);
  int fidx = second ? init2[b] : init1[b];
  int lane = threadIdx.x;

  __shared__ float4 cpt[512];
  const float* xb = x + (size_t)b * 500 * 3;
  for (int p = lane; p < 500; p += 64) {
    cpt[p] = make_float4(xb[p * 3], xb[p * 3 + 1], xb[p * 3 + 2], 0.f);
  }
  __syncthreads();

  float px[8], py[8], pz[8], dist[8];
  int base = lane * 8;
#pragma unroll
  for (int j = 0; j < 8; ++j) {
    int p = base + j;
    bool ok = p < 500;
    float4 c = cpt[ok ? p : 0];
    px[j] = c.x; py[j] = c.y; pz[j] = c.z;
    dist[j] = ok ? 1e10f : -1.0f;
  }

  for (int t = 0; t < npoint; ++t) {
    if (lane == 0) out[t] = fidx;
    float4 c = cpt[fidx];
#pragma unroll
    for (int j = 0; j < 8; ++j) {
      float dx = __fsub_rn(px[j], c.x);
      float dy = __fsub_rn(py[j], c.y);
      float dz = __fsub_rn(pz[j], c.z);
      float d = __fadd_rn(__fadd_rn(__fmul_rn(dx, dx), __fmul_rn(dy, dy)),
                          __fmul_rn(dz, dz));
      dist[j] = fminf(dist[j], d);
    }
    float bv = dist[0];
    int bi = base;
#pragma unroll
    for (int j = 1; j < 8; ++j) {
      if (dist[j] > bv) { bv = dist[j]; bi = base + j; }
    }
#pragma unroll
    for (int off = 1; off < 64; off <<= 1) {
      float ov = __shfl_xor(bv, off, 64);
      int oi = __shfl_xor(bi, off, 64);
      if (ov > bv || (ov == bv && oi < bi)) { bv = ov; bi = oi; }
    }
    fidx = bi;
  }
}

// ---------------------------------------------------------------------------
// VALU GEMM: out = act(A' @ W^T + bias). A (intermediates) is bf16; W, bias,
// X (raw coords) are FP32. A' row construction by mode:
//  0: plain A[M x K] bf16, row stride lda
//  1: stage-B gather: row r -> b=r/500, p=r%500, s=idx[b*500+p], srow=b*500+s
//     cols [0,lda) from A[srow], cols [lda,lda+3) from X[srow], else 0
//  2: stage-C gather: row r -> b=r>>10, p=r&1023 (p>=1000 => zero row),
//     s=idx[b*1000+p], srow=b*500+s; same concat layout as mode 1
// act: 0 none, 1 relu, 2 relu + per-batch column max -> atomicMax(outf)
// Tile: 64x64, BK=32, 256 threads, 4x4 micro-tile strided by 16.
// ---------------------------------------------------------------------------
#define TK 32

__global__ __launch_bounds__(256) void gemm_valu(
    const u16* __restrict__ A, int lda, const float* __restrict__ X,
    const int* __restrict__ idx, int mode, const float* __restrict__ W,
    const float* __restrict__ bias, u16* __restrict__ C, int ldc, int M,
    int K, int N, int act, float* __restrict__ outf) {
  __shared__ float sA[64][36];  // row stride 36 floats = 144B
  __shared__ float sW[64][36];
  __shared__ float red[16][64];

  const int t = threadIdx.x;
  const int m0 = blockIdx.x * 64;
  const int n0 = blockIdx.y * 64;
  const int tr = t >> 4;  // 0..15
  const int tc = t & 15;  // 0..15

  // staging coords: thread loads 8 consecutive k for one row
  const int srow = t >> 2;     // 0..63
  const int kc = (t & 3) * 8;  // 0,8,16,24

  const int ar = m0 + srow;
  const u16* aptr;
  const float* xptr = nullptr;
  bool valid = true;
  if (mode == 0) {
    aptr = A + (size_t)ar * lda;
  } else if (mode == 1) {
    int b = ar / 500;
    int p = ar - b * 500;
    int s = idx[b * 500 + p];
    size_t sr = (size_t)b * 500 + s;
    aptr = A + sr * lda;
    xptr = X + sr * 3;
  } else {
    int b = ar >> 10;
    int p = ar & 1023;
    valid = (p < 1000);
    int s = valid ? idx[b * 1000 + p] : 0;
    size_t sr = (size_t)b * 500 + s;
    aptr = A + sr * lda;
    xptr = X + sr * 3;
  }
  const float* wptr = W + (size_t)(n0 + srow) * K;

  float acc[4][4];
#pragma unroll
  for (int r = 0; r < 4; ++r)
#pragma unroll
    for (int c = 0; c < 4; ++c) acc[r][c] = 0.f;

  for (int k0 = 0; k0 < K; k0 += TK) {
    __syncthreads();
#pragma unroll
    for (int j = 0; j < 8; ++j) {
      int k = k0 + kc + j;
      float v = 0.f;
      if (mode == 0) {
        if (k < K) v = bf2f(aptr[k]);
      } else {
        if (valid) {
          if (k < lda) v = bf2f(aptr[k]);
          else if (k < lda + 3) v = xptr[k - lda];
        }
      }
      sA[srow][kc + j] = v;
      sW[srow][kc + j] = (k < K) ? wptr[k] : 0.f;
    }
    __syncthreads();
#pragma unroll
    for (int kq = 0; kq < 8; ++kq) {
      float4 av[4], wv[4];
#pragma unroll
      for (int r = 0; r < 4; ++r)
        av[r] = *(const float4*)&sA[tr + r * 16][kq * 4];
#pragma unroll
      for (int c = 0; c < 4; ++c)
        wv[c] = *(const float4*)&sW[tc + c * 16][kq * 4];
#pragma unroll
      for (int r = 0; r < 4; ++r)
#pragma unroll
        for (int c = 0; c < 4; ++c)
          acc[r][c] += av[r].x * wv[c].x + av[r].y * wv[c].y +
                       av[r].z * wv[c].z + av[r].w * wv[c].w;
    }
  }

  if (act < 2) {
#pragma unroll
    for (int c = 0; c < 4; ++c) {
      int gcol = n0 + tc + c * 16;
      float bv = bias[gcol];
#pragma unroll
      for (int r = 0; r < 4; ++r) {
        int grow = m0 + tr + r * 16;
        float v = acc[r][c] + bv;
        if (act == 1) v = fmaxf(v, 0.f);
        C[(size_t)grow * ldc + gcol] = f2bf(v);
      }
    }
  } else {
#pragma unroll
    for (int c = 0; c < 4; ++c) {
      int gcol = n0 + tc + c * 16;
      float bv = bias[gcol];
      float mx = 0.f;
#pragma unroll
      for (int r = 0; r < 4; ++r) {
        int grow = m0 + tr + r * 16;
        float v = fmaxf(acc[r][c] + bv, 0.f);
        if ((grow & 1023) < 1000) mx = fmaxf(mx, v);
      }
      red[tr][tc + c * 16] = mx;
    }
    __syncthreads();
    if (t < 64) {
      float m = red[0][t];
#pragma unroll
      for (int i = 1; i < 16; ++i) m = fmaxf(m, red[i][t]);
      int b = m0 >> 10;
      // relu values are >= 0, so uint-compare == float-compare
      atomicMax((unsigned*)&outf[b * 512 + n0 + t], __float_as_uint(m));
    }
  }
}

__global__ void zero_kernel(float* __restrict__ p, int n) {
  int i = blockIdx.x * 256 + threadIdx.x;
  if (i < n) p[i] = 0.f;
}

// ---------------------------------------------------------------------------
extern "C" void kernel_launch(void* const* d_in, const int* in_sizes, int n_in,
                              void* d_out, int out_size, void* d_ws,
                              size_t ws_size, hipStream_t stream) {
  const float* x      = (const float*)d_in[0];
  const float* conf_W = (const float*)d_in[1];
  const float* conf_b = (const float*)d_in[2];
  const float* w1     = (const float*)d_in[3];
  const float* b1     = (const float*)d_in[4];
  const float* w2     = (const float*)d_in[5];
  const float* b2     = (const float*)d_in[6];
  const float* pc1_W  = (const float*)d_in[7];
  const float* pc1_b  = (const float*)d_in[8];
  const float* w3     = (const float*)d_in[9];
  const float* b3     = (const float*)d_in[10];
  const float* w4     = (const float*)d_in[11];
  const float* b4     = (const float*)d_in[12];
  const float* pc2_W  = (const float*)d_in[13];
  const float* pc2_b  = (const float*)d_in[14];
  const float* w5     = (const float*)d_in[15];
  const float* b5     = (const float*)d_in[16];
  const float* w6     = (const float*)d_in[17];
  const float* b6     = (const float*)d_in[18];
  const int* init1    = (const int*)d_in[20];
  const int* init2    = (const int*)d_in[21];

  char* ws = (char*)d_ws;
  // arena A: feat -> l2 -> l4 -> l6 ; arena B: l1 -> l3 -> l5 -> l7
  u16* feat = (u16*)(ws + 0);
  u16* l2b  = (u16*)(ws + 0);
  u16* l4b  = (u16*)(ws + 0);
  u16* l6b  = (u16*)(ws + 0);
  u16* l1b  = (u16*)(ws + OFF_ARENA_B);
  u16* l3b  = (u16*)(ws + OFF_ARENA_B);
  u16* l5b  = (u16*)(ws + OFF_ARENA_B);
  u16* l7b  = (u16*)(ws + OFF_ARENA_B);
  int* idx1 = (int*)(ws + OFF_IDX1);
  int* idx2 = (int*)(ws + OFF_IDX2);
  float* outf = (float*)d_out;   // 128x512 fp32, accumulated via atomicMax

  fps_kernel<<<256, 64, 0, stream>>>(x, init1, init2, idx1, idx2);
  feat_kernel<<<250, 256, 0, stream>>>(x, conf_W, conf_b, feat);
  zero_kernel<<<256, 256, 0, stream>>>(outf, 65536);

  // stage A
  gemm_valu<<<dim3(1000, 1), 256, 0, stream>>>(feat, 4, nullptr, nullptr, 0,
                                               w1, b1, l1b, 64, M_AB, 4, 64, 1, nullptr);
  gemm_valu<<<dim3(1000, 4), 256, 0, stream>>>(l1b, 64, nullptr, nullptr, 0,
                                               w2, b2, l2b, 256, M_AB, 64, 256, 1, nullptr);
  gemm_valu<<<dim3(1000, 4), 256, 0, stream>>>(l2b, 256, nullptr, nullptr, 0,
                                               pc1_W, pc1_b, l3b, 256, M_AB, 256, 256, 0, nullptr);
  // stage B (gather fused into A-stager, mode 1)
  gemm_valu<<<dim3(1000, 4), 256, 0, stream>>>(l3b, 256, x, idx1, 1,
                                               w3, b3, l4b, 256, M_AB, 259, 256, 1, nullptr);
  gemm_valu<<<dim3(1000, 6), 256, 0, stream>>>(l4b, 256, nullptr, nullptr, 0,
                                               w4, b4, l5b, 384, M_AB, 256, 384, 1, nullptr);
  gemm_valu<<<dim3(1000, 6), 256, 0, stream>>>(l5b, 384, nullptr, nullptr, 0,
                                               pc2_W, pc2_b, l6b, 384, M_AB, 384, 384, 0, nullptr);
  // stage C (gather fused, mode 2; rows padded to 1024/batch)
  gemm_valu<<<dim3(2048, 6), 256, 0, stream>>>(l6b, 384, x, idx2, 2,
                                               w5, b5, l7b, 384, M_C, 387, 384, 1, nullptr);
  gemm_valu<<<dim3(2048, 8), 256, 0, stream>>>(l7b, 384, nullptr, nullptr, 0,
                                               w6, b6, nullptr, 0, M_C, 384, 512, 2, outf);
}

// Round 5
// 1326.785 us; speedup vs baseline: 4.2393x; 4.2393x over previous
//
#include <hip/hip_runtime.h>

typedef unsigned short u16;
typedef short bf16x8 __attribute__((ext_vector_type(8)));   // 8 bf16 (4 VGPRs), guide-verified operand type
typedef float f32x4 __attribute__((ext_vector_type(4)));
typedef unsigned short us8 __attribute__((ext_vector_type(8)));

__device__ __forceinline__ float bf2f(u16 u) {
  return __uint_as_float(((unsigned)u) << 16);
}
__device__ __forceinline__ u16 f2bf(float f) {
  unsigned u = __float_as_uint(f);
  u += 0x7fffu + ((u >> 16) & 1u);  // RNE (no NaNs in this workload)
  return (u16)(u >> 16);
}

// ---------------------------------------------------------------------------
// B=128, N=500. Stage A/B rows = 64000; stage C rows padded to 1024/batch.
// External buffers fp32; ws intermediates bf16.
// ---------------------------------------------------------------------------
#define M_AB 64000
#define M_C 131072

// ws layout (bytes), peak ~152.1 MB:
// arena A @ 0          : feat -> l2 -> l4 -> l6 (max 49,152,000)
// arena B @ 49,152,000 : l1 -> l3 -> l5 -> l7  (max 100,663,296)
#define OFF_ARENA_B 49152000u
#define OFF_IDX1 149815296u   // 128x500  int
#define OFF_IDX2 150071296u   // 128x1000 int
#define OFF_WB   150583296u   // bf16 weight arena (K padded), 1,519,616 B
// weight sub-offsets (bytes from OFF_WB); all 16B-aligned
#define WB1   0u        // 64 x 32    =   4,096
#define WB2   4096u     // 256 x 64   =  32,768
#define WBP1  36864u    // 256 x 256  = 131,072
#define WB3   167936u   // 256 x 288  = 147,456
#define WB4   315392u   // 384 x 256  = 196,608
#define WBP2  512000u   // 384 x 384  = 294,912
#define WB5   806912u   // 384 x 416  = 319,488
#define WB6   1126400u  // 512 x 384  = 393,216

// ---------------------------------------------------------------------------
// fp32 weight (N,K) -> bf16 (N,Kp) zero-padded
// ---------------------------------------------------------------------------
__global__ void convert_w(const float* __restrict__ src, u16* __restrict__ dst,
                          int N, int K, int Kp) {
  int i = blockIdx.x * 256 + threadIdx.x;
  if (i >= N * Kp) return;
  int n = i / Kp;
  int k = i - n * Kp;
  dst[i] = (k < K) ? f2bf(src[n * K + k]) : (u16)0;
}

// ---------------------------------------------------------------------------
// feat = [sigmoid(x@cW^T+cb), x]  (64000 x 4, bf16)
// ---------------------------------------------------------------------------
__global__ void feat_kernel(const float* __restrict__ x,
                            const float* __restrict__ cW,
                            const float* __restrict__ cb,
                            u16* __restrict__ feat) {
  int i = blockIdx.x * 256 + threadIdx.x;
  if (i >= M_AB) return;
  float x0 = x[i * 3], x1 = x[i * 3 + 1], x2 = x[i * 3 + 2];
  float z = x0 * cW[0] + x1 * cW[1] + x2 * cW[2] + cb[0];
  float conf = 1.0f / (1.0f + expf(-z));
  feat[i * 4 + 0] = f2bf(conf);
  feat[i * 4 + 1] = f2bf(x0);
  feat[i * 4 + 2] = f2bf(x1);
  feat[i * 4 + 3] = f2bf(x2);
}

// ---------------------------------------------------------------------------
// FPS: one wave per (batch, which-fps). Exact fp32 (_rn ops, np sum order),
// first-max tie-break = np.argmax.
// ---------------------------------------------------------------------------
__global__ __launch_bounds__(64) void fps_kernel(
    const float* __restrict__ x, const int* __restrict__ init1,
    const int* __restrict__ init2, int* __restrict__ idx1,
    int* __restrict__ idx2) {
  int bb = blockIdx.x;  // 0..255
  int b = bb & 127;
  bool second = bb >= 128;
  int npoint = second ? 1000 : 500;
  int* out = second ? (idx2 + b * 1000) : (idx1 + b * 500);
  int fidx = second ? init2[b] : init1[b];
  int lane = threadIdx.x;

  __shared__ float4 cpt[512];
  const float* xb = x + (size_t)b * 500 * 3;
  for (int p = lane; p < 500; p += 64) {
    cpt[p] = make_float4(xb[p * 3], xb[p * 3 + 1], xb[p * 3 + 2], 0.f);
  }
  __syncthreads();

  float px[8], py[8], pz[8], dist[8];
  int base = lane * 8;
#pragma unroll
  for (int j = 0; j < 8; ++j) {
    int p = base + j;
    bool ok = p < 500;
    float4 c = cpt[ok ? p : 0];
    px[j] = c.x; py[j] = c.y; pz[j] = c.z;
    dist[j] = ok ? 1e10f : -1.0f;
  }

  for (int t = 0; t < npoint; ++t) {
    if (lane == 0) out[t] = fidx;
    float4 c = cpt[fidx];
#pragma unroll
    for (int j = 0; j < 8; ++j) {
      float dx = __fsub_rn(px[j], c.x);
      float dy = __fsub_rn(py[j], c.y);
      float dz = __fsub_rn(pz[j], c.z);
      float d = __fadd_rn(__fadd_rn(__fmul_rn(dx, dx), __fmul_rn(dy, dy)),
                          __fmul_rn(dz, dz));
      dist[j] = fminf(dist[j], d);
    }
    float bv = dist[0];
    int bi = base;
#pragma unroll
    for (int j = 1; j < 8; ++j) {
      if (dist[j] > bv) { bv = dist[j]; bi = base + j; }
    }
#pragma unroll
    for (int off = 1; off < 64; off <<= 1) {
      float ov = __shfl_xor(bv, off, 64);
      int oi = __shfl_xor(bi, off, 64);
      if (ov > bv || (ov == bv && oi < bi)) { bv = ov; bi = oi; }
    }
    fidx = bi;
  }
}

// ---------------------------------------------------------------------------
// MFMA GEMM: C = act(A' @ Wb^T + bias). A' bf16 (with optional fused gather +
// fp32-x concat), Wb bf16 [N][Kp] (pre-padded). 128x128 tile, BK=32,
// 4 waves, each wave 64x64 via 4x4 grid of 16x16x32 MFMAs.
// mode: 0 plain; 1 stage-B gather (b=r/500); 2 stage-C gather (b=r>>10,
//       p=r&1023, p>=1000 -> zero row). act: 0 none, 1 relu,
//       2 relu + per-batch col max -> atomicMax(outf) [assumes 1024 rows/b].
// ---------------------------------------------------------------------------
#define LDT 40  // LDS row stride elems (80 B): 2-way bank alias on frag reads = free

__global__ __launch_bounds__(256) void gemm_mfma(
    const u16* __restrict__ A, int lda, const float* __restrict__ X,
    const int* __restrict__ idx, int mode, const u16* __restrict__ Wb,
    int ldw, const float* __restrict__ bias, u16* __restrict__ C, int ldc,
    int M, int K, int Kp, int N, int act, float* __restrict__ outf) {
  __shared__ __align__(16) u16 lA[128 * LDT];
  __shared__ __align__(16) u16 lB[128 * LDT];
  __shared__ float red[2][128];

  const int t = threadIdx.x;
  const int m0 = blockIdx.x * 128;
  const int n0 = blockIdx.y * 128;
  const int w = t >> 6;
  const int lane = t & 63;
  const int mrow = lane & 15;
  const int quad = lane >> 4;
  const int wm = w >> 1;  // 0..1
  const int wn = w & 1;   // 0..1

  // staging: thread covers rows crow and crow+64, 8 k-elems at kc
  const int crow = t >> 2;       // 0..63
  const int kc = (t & 3) * 8;    // 0,8,16,24

  // resolve A row pointers (loop-invariant)
  const u16* aptr[2];
  const float* xptr[2] = {nullptr, nullptr};
  bool valid[2] = {true, true};
#pragma unroll
  for (int h = 0; h < 2; ++h) {
    int gr = m0 + crow + h * 64;
    if (mode == 0) {
      aptr[h] = A + (size_t)gr * lda;
    } else if (mode == 1) {
      int b = gr / 500;
      int p = gr - b * 500;
      int s = idx[b * 500 + p];
      size_t sr = (size_t)b * 500 + s;
      aptr[h] = A + sr * lda;
      xptr[h] = X + sr * 3;
    } else {
      int b = gr >> 10;
      int p = gr & 1023;
      valid[h] = (p < 1000);
      int s = valid[h] ? idx[b * 1000 + p] : 0;
      size_t sr = (size_t)b * 500 + s;
      aptr[h] = A + sr * lda;
      xptr[h] = X + sr * 3;
    }
  }
  const u16* wptr[2];
  bool wvalid[2];
#pragma unroll
  for (int h = 0; h < 2; ++h) {
    int wr = n0 + crow + h * 64;
    wvalid[h] = (wr < N);
    wptr[h] = Wb + (size_t)(wvalid[h] ? wr : 0) * ldw;
  }

  f32x4 acc[4][4];
  const f32x4 fz = {0.f, 0.f, 0.f, 0.f};
#pragma unroll
  for (int i = 0; i < 4; ++i)
#pragma unroll
    for (int j = 0; j < 4; ++j) acc[i][j] = fz;

  for (int k0 = 0; k0 < Kp; k0 += 32) {
    __syncthreads();
    int kk = k0 + kc;
#pragma unroll
    for (int h = 0; h < 2; ++h) {
      // ---- A tile row crow + h*64
      us8 va;
      if (mode == 0) {
        if (kk + 8 <= K) {
          va = *(const us8*)(aptr[h] + kk);
        } else {
#pragma unroll
          for (int j = 0; j < 8; ++j)
            va[j] = (kk + j < K) ? aptr[h][kk + j] : (u16)0;
        }
      } else {
        if (valid[h] && kk + 8 <= lda) {
          va = *(const us8*)(aptr[h] + kk);
        } else {
#pragma unroll
          for (int j = 0; j < 8; ++j) {
            int k = kk + j;
            u16 v = 0;
            if (valid[h]) {
              if (k < lda) v = aptr[h][k];
              else if (k < lda + 3) v = f2bf(xptr[h][k - lda]);
            }
            va[j] = v;
          }
        }
      }
      *(us8*)(lA + (crow + h * 64) * LDT + kc) = va;
      // ---- W tile row crow + h*64 (Kp-padded: vector load always in-range)
      us8 vb = {0, 0, 0, 0, 0, 0, 0, 0};
      if (wvalid[h]) vb = *(const us8*)(wptr[h] + kk);
      *(us8*)(lB + (crow + h * 64) * LDT + kc) = vb;
    }
    __syncthreads();

    const u16* aBase = lA + (wm * 64 + mrow) * LDT + quad * 8;
    const u16* bBase = lB + (wn * 64 + mrow) * LDT + quad * 8;
    bf16x8 af[4], bfv[4];
#pragma unroll
    for (int mi = 0; mi < 4; ++mi) af[mi] = *(const bf16x8*)(aBase + mi * 16 * LDT);
#pragma unroll
    for (int ni = 0; ni < 4; ++ni) bfv[ni] = *(const bf16x8*)(bBase + ni * 16 * LDT);
#pragma unroll
    for (int mi = 0; mi < 4; ++mi)
#pragma unroll
      for (int ni = 0; ni < 4; ++ni)
        acc[mi][ni] = __builtin_amdgcn_mfma_f32_16x16x32_bf16(
            af[mi], bfv[ni], acc[mi][ni], 0, 0, 0);
  }

  if (act < 2) {
#pragma unroll
    for (int ni = 0; ni < 4; ++ni) {
      int col = n0 + wn * 64 + ni * 16 + mrow;
      if (col >= N) continue;
      float bv = bias[col];
#pragma unroll
      for (int mi = 0; mi < 4; ++mi)
#pragma unroll
        for (int r = 0; r < 4; ++r) {
          int grow = m0 + wm * 64 + mi * 16 + quad * 4 + r;
          float v = acc[mi][ni][r] + bv;
          if (act == 1) v = fmaxf(v, 0.f);
          C[(size_t)grow * ldc + col] = f2bf(v);
        }
    }
  } else {
#pragma unroll
    for (int ni = 0; ni < 4; ++ni) {
      int col = n0 + wn * 64 + ni * 16 + mrow;
      float bv = (col < N) ? bias[col] : 0.f;
      float mx = 0.f;
#pragma unroll
      for (int mi = 0; mi < 4; ++mi)
#pragma unroll
        for (int r = 0; r < 4; ++r) {
          int grow = m0 + wm * 64 + mi * 16 + quad * 4 + r;
          float v = fmaxf(acc[mi][ni][r] + bv, 0.f);
          if ((grow & 1023) < 1000) mx = fmaxf(mx, v);
        }
      mx = fmaxf(mx, __shfl_xor(mx, 16, 64));
      mx = fmaxf(mx, __shfl_xor(mx, 32, 64));
      if (quad == 0) red[wm][wn * 64 + ni * 16 + mrow] = mx;
    }
    __syncthreads();
    if (t < 128) {
      int col = n0 + t;
      if (col < N) {
        float m = fmaxf(red[0][t], red[1][t]);
        int b = m0 >> 10;
        // relu outputs >= 0: uint compare == float compare
        atomicMax((unsigned*)&outf[b * 512 + col], __float_as_uint(m));
      }
    }
  }
}

__global__ void zero_kernel(float* __restrict__ p, int n) {
  int i = blockIdx.x * 256 + threadIdx.x;
  if (i < n) p[i] = 0.f;
}

// ---------------------------------------------------------------------------
extern "C" void kernel_launch(void* const* d_in, const int* in_sizes, int n_in,
                              void* d_out, int out_size, void* d_ws,
                              size_t ws_size, hipStream_t stream) {
  const float* x      = (const float*)d_in[0];
  const float* conf_W = (const float*)d_in[1];
  const float* conf_b = (const float*)d_in[2];
  const float* w1     = (const float*)d_in[3];
  const float* b1     = (const float*)d_in[4];
  const float* w2     = (const float*)d_in[5];
  const float* b2     = (const float*)d_in[6];
  const float* pc1_W  = (const float*)d_in[7];
  const float* pc1_b  = (const float*)d_in[8];
  const float* w3     = (const float*)d_in[9];
  const float* b3     = (const float*)d_in[10];
  const float* w4     = (const float*)d_in[11];
  const float* b4     = (const float*)d_in[12];
  const float* pc2_W  = (const float*)d_in[13];
  const float* pc2_b  = (const float*)d_in[14];
  const float* w5     = (const float*)d_in[15];
  const float* b5     = (const float*)d_in[16];
  const float* w6     = (const float*)d_in[17];
  const float* b6     = (const float*)d_in[18];
  const int* init1    = (const int*)d_in[20];
  const int* init2    = (const int*)d_in[21];

  char* ws = (char*)d_ws;
  u16* feat = (u16*)(ws + 0);
  u16* l2b  = (u16*)(ws + 0);
  u16* l4b  = (u16*)(ws + 0);
  u16* l6b  = (u16*)(ws + 0);
  u16* l1b  = (u16*)(ws + OFF_ARENA_B);
  u16* l3b  = (u16*)(ws + OFF_ARENA_B);
  u16* l5b  = (u16*)(ws + OFF_ARENA_B);
  u16* l7b  = (u16*)(ws + OFF_ARENA_B);
  int* idx1 = (int*)(ws + OFF_IDX1);
  int* idx2 = (int*)(ws + OFF_IDX2);
  u16* wb   = (u16*)(ws + OFF_WB);
  u16* wb1  = wb + WB1 / 2;
  u16* wb2  = wb + WB2 / 2;
  u16* wbp1 = wb + WBP1 / 2;
  u16* wb3  = wb + WB3 / 2;
  u16* wb4  = wb + WB4 / 2;
  u16* wbp2 = wb + WBP2 / 2;
  u16* wb5  = wb + WB5 / 2;
  u16* wb6  = wb + WB6 / 2;
  float* outf = (float*)d_out;  // 128x512 fp32 accumulated via atomicMax

  fps_kernel<<<256, 64, 0, stream>>>(x, init1, init2, idx1, idx2);
  feat_kernel<<<250, 256, 0, stream>>>(x, conf_W, conf_b, feat);
  zero_kernel<<<256, 256, 0, stream>>>(outf, 65536);

  convert_w<<<(64 * 32 + 255) / 256, 256, 0, stream>>>(w1, wb1, 64, 4, 32);
  convert_w<<<(256 * 64 + 255) / 256, 256, 0, stream>>>(w2, wb2, 256, 64, 64);
  convert_w<<<(256 * 256 + 255) / 256, 256, 0, stream>>>(pc1_W, wbp1, 256, 256, 256);
  convert_w<<<(256 * 288 + 255) / 256, 256, 0, stream>>>(w3, wb3, 256, 259, 288);
  convert_w<<<(384 * 256 + 255) / 256, 256, 0, stream>>>(w4, wb4, 384, 256, 256);
  convert_w<<<(384 * 384 + 255) / 256, 256, 0, stream>>>(pc2_W, wbp2, 384, 384, 384);
  convert_w<<<(384 * 416 + 255) / 256, 256, 0, stream>>>(w5, wb5, 384, 387, 416);
  convert_w<<<(512 * 384 + 255) / 256, 256, 0, stream>>>(w6, wb6, 512, 384, 384);

  // stage A
  gemm_mfma<<<dim3(500, 1), 256, 0, stream>>>(feat, 4, nullptr, nullptr, 0,
      wb1, 32, b1, l1b, 64, M_AB, 4, 32, 64, 1, nullptr);
  gemm_mfma<<<dim3(500, 2), 256, 0, stream>>>(l1b, 64, nullptr, nullptr, 0,
      wb2, 64, b2, l2b, 256, M_AB, 64, 64, 256, 1, nullptr);
  gemm_mfma<<<dim3(500, 2), 256, 0, stream>>>(l2b, 256, nullptr, nullptr, 0,
      wbp1, 256, pc1_b, l3b, 256, M_AB, 256, 256, 256, 0, nullptr);
  // stage B (gather fused, mode 1)
  gemm_mfma<<<dim3(500, 2), 256, 0, stream>>>(l3b, 256, x, idx1, 1,
      wb3, 288, b3, l4b, 256, M_AB, 259, 288, 256, 1, nullptr);
  gemm_mfma<<<dim3(500, 3), 256, 0, stream>>>(l4b, 256, nullptr, nullptr, 0,
      wb4, 256, b4, l5b, 384, M_AB, 256, 256, 384, 1, nullptr);
  gemm_mfma<<<dim3(500, 3), 256, 0, stream>>>(l5b, 384, nullptr, nullptr, 0,
      wbp2, 384, pc2_b, l6b, 384, M_AB, 384, 384, 384, 0, nullptr);
  // stage C (gather fused, mode 2; rows padded to 1024/batch)
  gemm_mfma<<<dim3(1024, 3), 256, 0, stream>>>(l6b, 384, x, idx2, 2,
      wb5, 416, b5, l7b, 384, M_C, 387, 416, 384, 1, nullptr);
  gemm_mfma<<<dim3(1024, 4), 256, 0, stream>>>(l7b, 384, nullptr, nullptr, 0,
      wb6, 384, b6, nullptr, 0, M_C, 384, 384, 512, 2, outf);
}

// Round 6
// 832.619 us; speedup vs baseline: 6.7553x; 1.5935x over previous
//
#include <hip/hip_runtime.h>

typedef unsigned short u16;
typedef short bf16x8 __attribute__((ext_vector_type(8)));   // 8 bf16 (4 VGPRs), guide-verified operand type
typedef float f32x4 __attribute__((ext_vector_type(4)));
typedef unsigned short us8 __attribute__((ext_vector_type(8)));
typedef unsigned long long u64;

__device__ __forceinline__ float bf2f(u16 u) {
  return __uint_as_float(((unsigned)u) << 16);
}
__device__ __forceinline__ u16 f2bf(float f) {
  unsigned u = __float_as_uint(f);
  u += 0x7fffu + ((u >> 16) & 1u);  // RNE (no NaNs in this workload)
  return (u16)(u >> 16);
}

// ---------------------------------------------------------------------------
// B=128, N=500. Stage A/B rows = 64000; stage C rows padded to 1024/batch.
// External buffers fp32; ws intermediates bf16.
// ---------------------------------------------------------------------------
#define M_AB 64000
#define M_C 131072

// ws layout (bytes), peak ~152.1 MB:
// arena A @ 0          : feat -> l2 -> l4 -> l6 (max 49,152,000)
// arena B @ 49,152,000 : l1 -> l3 -> l5 -> l7  (max 100,663,296)
#define OFF_ARENA_B 49152000u
#define OFF_IDX1 149815296u   // 128x500  int
#define OFF_IDX2 150071296u   // 128x1000 int
#define OFF_WB   150583296u   // bf16 weight arena (K padded), 1,519,616 B
// weight sub-offsets (bytes from OFF_WB); all 16B-aligned
#define WB1   0u        // 64 x 32    =   4,096
#define WB2   4096u     // 256 x 64   =  32,768
#define WBP1  36864u    // 256 x 256  = 131,072
#define WB3   167936u   // 256 x 288  = 147,456
#define WB4   315392u   // 384 x 256  = 196,608
#define WBP2  512000u   // 384 x 384  = 294,912
#define WB5   806912u   // 384 x 416  = 319,488
#define WB6   1126400u  // 512 x 384  = 393,216

// ---------------------------------------------------------------------------
// fp32 weight (N,K) -> bf16 (N,Kp) zero-padded
// ---------------------------------------------------------------------------
__global__ void convert_w(const float* __restrict__ src, u16* __restrict__ dst,
                          int N, int K, int Kp) {
  int i = blockIdx.x * 256 + threadIdx.x;
  if (i >= N * Kp) return;
  int n = i / Kp;
  int k = i - n * Kp;
  dst[i] = (k < K) ? f2bf(src[n * K + k]) : (u16)0;
}

// ---------------------------------------------------------------------------
// feat = [sigmoid(x@cW^T+cb), x]  (64000 x 4, bf16)
// ---------------------------------------------------------------------------
__global__ void feat_kernel(const float* __restrict__ x,
                            const float* __restrict__ cW,
                            const float* __restrict__ cb,
                            u16* __restrict__ feat) {
  int i = blockIdx.x * 256 + threadIdx.x;
  if (i >= M_AB) return;
  float x0 = x[i * 3], x1 = x[i * 3 + 1], x2 = x[i * 3 + 2];
  float z = x0 * cW[0] + x1 * cW[1] + x2 * cW[2] + cb[0];
  float conf = 1.0f / (1.0f + expf(-z));
  feat[i * 4 + 0] = f2bf(conf);
  feat[i * 4 + 1] = f2bf(x0);
  feat[i * 4 + 2] = f2bf(x1);
  feat[i * 4 + 3] = f2bf(x2);
}

// ---------------------------------------------------------------------------
// FPS: one wave per (batch, which-fps). Exact fp32 (_rn ops, np sum order).
// Argmax via u64 keys (dist_bits<<32 | ~p): max key == max dist with
// smallest-index tie-break (np.argmax). Wave reduce via DPP row_shr/bcast
// (VALU latency) instead of ds_bpermute shuffles. Early exit when max dist
// hits 0 (all points selected): remaining emissions are argmax(0s) = 0.
// ---------------------------------------------------------------------------
__device__ __forceinline__ u64 kmax(u64 a, u64 b) { return a > b ? a : b; }

template <int CTRL>
__device__ __forceinline__ u64 dpp_max_step(u64 k) {
  unsigned lo = (unsigned)k, hi = (unsigned)(k >> 32);
  unsigned slo = (unsigned)__builtin_amdgcn_update_dpp(0, (int)lo, CTRL, 0xF, 0xF, true);
  unsigned shi = (unsigned)__builtin_amdgcn_update_dpp(0, (int)hi, CTRL, 0xF, 0xF, true);
  u64 sk = ((u64)shi << 32) | slo;
  return kmax(k, sk);
}

__global__ __launch_bounds__(64) void fps_kernel(
    const float* __restrict__ x, const int* __restrict__ init1,
    const int* __restrict__ init2, int* __restrict__ idx1,
    int* __restrict__ idx2) {
  int bb = blockIdx.x;  // 0..255
  int b = bb & 127;
  bool second = bb >= 128;
  int npoint = second ? 1000 : 500;
  int* out = second ? (idx2 + b * 1000) : (idx1 + b * 500);
  int fidx = second ? init2[b] : init1[b];
  int lane = threadIdx.x;

  __shared__ float4 cpt[512];
  const float* xb = x + (size_t)b * 500 * 3;
  for (int p = lane; p < 500; p += 64) {
    cpt[p] = make_float4(xb[p * 3], xb[p * 3 + 1], xb[p * 3 + 2], 0.f);
  }
  __syncthreads();

  float px[8], py[8], pz[8], dist[8];
  unsigned lok[8];  // low key word: ~p for valid, 0 for dup slots (can't win vs real p)
  int base = lane * 8;
#pragma unroll
  for (int j = 0; j < 8; ++j) {
    int p = base + j;
    bool ok = p < 500;
    float4 c = cpt[ok ? p : 0];  // invalid slots duplicate point 0
    px[j] = c.x; py[j] = c.y; pz[j] = c.z;
    dist[j] = 1e10f;
    lok[j] = ok ? ~(unsigned)p : 0u;
  }

  for (int t = 0; t < npoint; ++t) {
    if (lane == 0) out[t] = fidx;
    if (t == npoint - 1) break;
    float4 c = cpt[fidx];
    u64 key[8];
#pragma unroll
    for (int j = 0; j < 8; ++j) {
      float dx = __fsub_rn(px[j], c.x);
      float dy = __fsub_rn(py[j], c.y);
      float dz = __fsub_rn(pz[j], c.z);
      float d = __fadd_rn(__fadd_rn(__fmul_rn(dx, dx), __fmul_rn(dy, dy)),
                          __fmul_rn(dz, dz));
      dist[j] = fminf(dist[j], d);
      key[j] = ((u64)__float_as_uint(dist[j]) << 32) | lok[j];
    }
    // 3-level local tree
    u64 k01 = kmax(key[0], key[1]), k23 = kmax(key[2], key[3]);
    u64 k45 = kmax(key[4], key[5]), k67 = kmax(key[6], key[7]);
    u64 k = kmax(kmax(k01, k23), kmax(k45, k67));
    // wave reduce: row_shr 1,2,4,8 then row_bcast 15,31 -> lane 63 has max
    k = dpp_max_step<0x111>(k);
    k = dpp_max_step<0x112>(k);
    k = dpp_max_step<0x114>(k);
    k = dpp_max_step<0x118>(k);
    k = dpp_max_step<0x142>(k);
    k = dpp_max_step<0x143>(k);
    unsigned wlo = (unsigned)__builtin_amdgcn_readlane((int)(unsigned)k, 63);
    unsigned whi = (unsigned)__builtin_amdgcn_readlane((int)(unsigned)(k >> 32), 63);
    fidx = (int)~wlo;
    if (whi == 0u) {  // max dist == 0 -> all dists 0 -> argmax stays 0 forever
      for (int tt = t + 1 + lane; tt < npoint; tt += 64) out[tt] = 0;
      break;
    }
  }
}

// ---------------------------------------------------------------------------
// MFMA GEMM: C = act(A' @ Wb^T + bias). A' bf16 (with optional fused gather +
// fp32-x concat), Wb bf16 [N][Kp] (pre-padded). 128x128 tile, BK=32,
// 4 waves, each wave 64x64 via 4x4 grid of 16x16x32 MFMAs.
// mode: 0 plain; 1 stage-B gather (b=r/500); 2 stage-C gather (b=r>>10,
//       p=r&1023, p>=1000 -> zero row). act: 0 none, 1 relu,
//       2 relu + per-batch col max -> atomicMax(outf) [assumes 1024 rows/b].
// ---------------------------------------------------------------------------
#define LDT 40  // LDS row stride elems (80 B): 2-way bank alias on frag reads = free

__global__ __launch_bounds__(256) void gemm_mfma(
    const u16* __restrict__ A, int lda, const float* __restrict__ X,
    const int* __restrict__ idx, int mode, const u16* __restrict__ Wb,
    int ldw, const float* __restrict__ bias, u16* __restrict__ C, int ldc,
    int M, int K, int Kp, int N, int act, float* __restrict__ outf) {
  __shared__ __align__(16) u16 lA[128 * LDT];
  __shared__ __align__(16) u16 lB[128 * LDT];
  __shared__ float red[2][128];

  const int t = threadIdx.x;
  const int m0 = blockIdx.x * 128;
  const int n0 = blockIdx.y * 128;
  const int w = t >> 6;
  const int lane = t & 63;
  const int mrow = lane & 15;
  const int quad = lane >> 4;
  const int wm = w >> 1;  // 0..1
  const int wn = w & 1;   // 0..1

  // staging: thread covers rows crow and crow+64, 8 k-elems at kc
  const int crow = t >> 2;       // 0..63
  const int kc = (t & 3) * 8;    // 0,8,16,24

  // resolve A row pointers (loop-invariant)
  const u16* aptr[2];
  const float* xptr[2] = {nullptr, nullptr};
  bool valid[2] = {true, true};
#pragma unroll
  for (int h = 0; h < 2; ++h) {
    int gr = m0 + crow + h * 64;
    if (mode == 0) {
      aptr[h] = A + (size_t)gr * lda;
    } else if (mode == 1) {
      int b = gr / 500;
      int p = gr - b * 500;
      int s = idx[b * 500 + p];
      size_t sr = (size_t)b * 500 + s;
      aptr[h] = A + sr * lda;
      xptr[h] = X + sr * 3;
    } else {
      int b = gr >> 10;
      int p = gr & 1023;
      valid[h] = (p < 1000);
      int s = valid[h] ? idx[b * 1000 + p] : 0;
      size_t sr = (size_t)b * 500 + s;
      aptr[h] = A + sr * lda;
      xptr[h] = X + sr * 3;
    }
  }
  const u16* wptr[2];
  bool wvalid[2];
#pragma unroll
  for (int h = 0; h < 2; ++h) {
    int wr = n0 + crow + h * 64;
    wvalid[h] = (wr < N);
    wptr[h] = Wb + (size_t)(wvalid[h] ? wr : 0) * ldw;
  }

  f32x4 acc[4][4];
  const f32x4 fz = {0.f, 0.f, 0.f, 0.f};
#pragma unroll
  for (int i = 0; i < 4; ++i)
#pragma unroll
    for (int j = 0; j < 4; ++j) acc[i][j] = fz;

  for (int k0 = 0; k0 < Kp; k0 += 32) {
    __syncthreads();
    int kk = k0 + kc;
#pragma unroll
    for (int h = 0; h < 2; ++h) {
      // ---- A tile row crow + h*64
      us8 va;
      if (mode == 0) {
        if (kk + 8 <= K) {
          va = *(const us8*)(aptr[h] + kk);
        } else {
#pragma unroll
          for (int j = 0; j < 8; ++j)
            va[j] = (kk + j < K) ? aptr[h][kk + j] : (u16)0;
        }
      } else {
        if (valid[h] && kk + 8 <= lda) {
          va = *(const us8*)(aptr[h] + kk);
        } else {
#pragma unroll
          for (int j = 0; j < 8; ++j) {
            int k = kk + j;
            u16 v = 0;
            if (valid[h]) {
              if (k < lda) v = aptr[h][k];
              else if (k < lda + 3) v = f2bf(xptr[h][k - lda]);
            }
            va[j] = v;
          }
        }
      }
      *(us8*)(lA + (crow + h * 64) * LDT + kc) = va;
      // ---- W tile row crow + h*64 (Kp-padded: vector load always in-range)
      us8 vb = {0, 0, 0, 0, 0, 0, 0, 0};
      if (wvalid[h]) vb = *(const us8*)(wptr[h] + kk);
      *(us8*)(lB + (crow + h * 64) * LDT + kc) = vb;
    }
    __syncthreads();

    const u16* aBase = lA + (wm * 64 + mrow) * LDT + quad * 8;
    const u16* bBase = lB + (wn * 64 + mrow) * LDT + quad * 8;
    bf16x8 af[4], bfv[4];
#pragma unroll
    for (int mi = 0; mi < 4; ++mi) af[mi] = *(const bf16x8*)(aBase + mi * 16 * LDT);
#pragma unroll
    for (int ni = 0; ni < 4; ++ni) bfv[ni] = *(const bf16x8*)(bBase + ni * 16 * LDT);
#pragma unroll
    for (int mi = 0; mi < 4; ++mi)
#pragma unroll
      for (int ni = 0; ni < 4; ++ni)
        acc[mi][ni] = __builtin_amdgcn_mfma_f32_16x16x32_bf16(
            af[mi], bfv[ni], acc[mi][ni], 0, 0, 0);
  }

  if (act < 2) {
#pragma unroll
    for (int ni = 0; ni < 4; ++ni) {
      int col = n0 + wn * 64 + ni * 16 + mrow;
      if (col >= N) continue;
      float bv = bias[col];
#pragma unroll
      for (int mi = 0; mi < 4; ++mi)
#pragma unroll
        for (int r = 0; r < 4; ++r) {
          int grow = m0 + wm * 64 + mi * 16 + quad * 4 + r;
          float v = acc[mi][ni][r] + bv;
          if (act == 1) v = fmaxf(v, 0.f);
          C[(size_t)grow * ldc + col] = f2bf(v);
        }
    }
  } else {
#pragma unroll
    for (int ni = 0; ni < 4; ++ni) {
      int col = n0 + wn * 64 + ni * 16 + mrow;
      float bv = (col < N) ? bias[col] : 0.f;
      float mx = 0.f;
#pragma unroll
      for (int mi = 0; mi < 4; ++mi)
#pragma unroll
        for (int r = 0; r < 4; ++r) {
          int grow = m0 + wm * 64 + mi * 16 + quad * 4 + r;
          float v = fmaxf(acc[mi][ni][r] + bv, 0.f);
          if ((grow & 1023) < 1000) mx = fmaxf(mx, v);
        }
      mx = fmaxf(mx, __shfl_xor(mx, 16, 64));
      mx = fmaxf(mx, __shfl_xor(mx, 32, 64));
      if (quad == 0) red[wm][wn * 64 + ni * 16 + mrow] = mx;
    }
    __syncthreads();
    if (t < 128) {
      int col = n0 + t;
      if (col < N) {
        float m = fmaxf(red[0][t], red[1][t]);
        int b = m0 >> 10;
        // relu outputs >= 0: uint compare == float compare
        atomicMax((unsigned*)&outf[b * 512 + col], __float_as_uint(m));
      }
    }
  }
}

__global__ void zero_kernel(float* __restrict__ p, int n) {
  int i = blockIdx.x * 256 + threadIdx.x;
  if (i < n) p[i] = 0.f;
}

// ---------------------------------------------------------------------------
extern "C" void kernel_launch(void* const* d_in, const int* in_sizes, int n_in,
                              void* d_out, int out_size, void* d_ws,
                              size_t ws_size, hipStream_t stream) {
  const float* x      = (const float*)d_in[0];
  const float* conf_W = (const float*)d_in[1];
  const float* conf_b = (const float*)d_in[2];
  const float* w1     = (const float*)d_in[3];
  const float* b1     = (const float*)d_in[4];
  const float* w2     = (const float*)d_in[5];
  const float* b2     = (const float*)d_in[6];
  const float* pc1_W  = (const float*)d_in[7];
  const float* pc1_b  = (const float*)d_in[8];
  const float* w3     = (const float*)d_in[9];
  const float* b3     = (const float*)d_in[10];
  const float* w4     = (const float*)d_in[11];
  const float* b4     = (const float*)d_in[12];
  const float* pc2_W  = (const float*)d_in[13];
  const float* pc2_b  = (const float*)d_in[14];
  const float* w5     = (const float*)d_in[15];
  const float* b5     = (const float*)d_in[16];
  const float* w6     = (const float*)d_in[17];
  const float* b6     = (const float*)d_in[18];
  const int* init1    = (const int*)d_in[20];
  const int* init2    = (const int*)d_in[21];

  char* ws = (char*)d_ws;
  u16* feat = (u16*)(ws + 0);
  u16* l2b  = (u16*)(ws + 0);
  u16* l4b  = (u16*)(ws + 0);
  u16* l6b  = (u16*)(ws + 0);
  u16* l1b  = (u16*)(ws + OFF_ARENA_B);
  u16* l3b  = (u16*)(ws + OFF_ARENA_B);
  u16* l5b  = (u16*)(ws + OFF_ARENA_B);
  u16* l7b  = (u16*)(ws + OFF_ARENA_B);
  int* idx1 = (int*)(ws + OFF_IDX1);
  int* idx2 = (int*)(ws + OFF_IDX2);
  u16* wb   = (u16*)(ws + OFF_WB);
  u16* wb1  = wb + WB1 / 2;
  u16* wb2  = wb + WB2 / 2;
  u16* wbp1 = wb + WBP1 / 2;
  u16* wb3  = wb + WB3 / 2;
  u16* wb4  = wb + WB4 / 2;
  u16* wbp2 = wb + WBP2 / 2;
  u16* wb5  = wb + WB5 / 2;
  u16* wb6  = wb + WB6 / 2;
  float* outf = (float*)d_out;  // 128x512 fp32 accumulated via atomicMax

  fps_kernel<<<256, 64, 0, stream>>>(x, init1, init2, idx1, idx2);
  feat_kernel<<<250, 256, 0, stream>>>(x, conf_W, conf_b, feat);
  zero_kernel<<<256, 256, 0, stream>>>(outf, 65536);

  convert_w<<<(64 * 32 + 255) / 256, 256, 0, stream>>>(w1, wb1, 64, 4, 32);
  convert_w<<<(256 * 64 + 255) / 256, 256, 0, stream>>>(w2, wb2, 256, 64, 64);
  convert_w<<<(256 * 256 + 255) / 256, 256, 0, stream>>>(pc1_W, wbp1, 256, 256, 256);
  convert_w<<<(256 * 288 + 255) / 256, 256, 0, stream>>>(w3, wb3, 256, 259, 288);
  convert_w<<<(384 * 256 + 255) / 256, 256, 0, stream>>>(w4, wb4, 384, 256, 256);
  convert_w<<<(384 * 384 + 255) / 256, 256, 0, stream>>>(pc2_W, wbp2, 384, 384, 384);
  convert_w<<<(384 * 416 + 255) / 256, 256, 0, stream>>>(w5, wb5, 384, 387, 416);
  convert_w<<<(512 * 384 + 255) / 256, 256, 0, stream>>>(w6, wb6, 512, 384, 384);

  // stage A
  gemm_mfma<<<dim3(500, 1), 256, 0, stream>>>(feat, 4, nullptr, nullptr, 0,
      wb1, 32, b1, l1b, 64, M_AB, 4, 32, 64, 1, nullptr);
  gemm_mfma<<<dim3(500, 2), 256, 0, stream>>>(l1b, 64, nullptr, nullptr, 0,
      wb2, 64, b2, l2b, 256, M_AB, 64, 64, 256, 1, nullptr);
  gemm_mfma<<<dim3(500, 2), 256, 0, stream>>>(l2b, 256, nullptr, nullptr, 0,
      wbp1, 256, pc1_b, l3b, 256, M_AB, 256, 256, 256, 0, nullptr);
  // stage B (gather fused, mode 1)
  gemm_mfma<<<dim3(500, 2), 256, 0, stream>>>(l3b, 256, x, idx1, 1,
      wb3, 288, b3, l4b, 256, M_AB, 259, 288, 256, 1, nullptr);
  gemm_mfma<<<dim3(500, 3), 256, 0, stream>>>(l4b, 256, nullptr, nullptr, 0,
      wb4, 256, b4, l5b, 384, M_AB, 256, 256, 384, 1, nullptr);
  gemm_mfma<<<dim3(500, 3), 256, 0, stream>>>(l5b, 384, nullptr, nullptr, 0,
      wbp2, 384, pc2_b, l6b, 384, M_AB, 384, 384, 384, 0, nullptr);
  // stage C (gather fused, mode 2; rows padded to 1024/batch)
  gemm_mfma<<<dim3(1024, 3), 256, 0, stream>>>(l6b, 384, x, idx2, 2,
      wb5, 416, b5, l7b, 384, M_C, 387, 416, 384, 1, nullptr);
  gemm_mfma<<<dim3(1024, 4), 256, 0, stream>>>(l7b, 384, nullptr, nullptr, 0,
      wb6, 384, b6, nullptr, 0, M_C, 384, 384, 512, 2, outf);
}

// Round 7
// 829.372 us; speedup vs baseline: 6.7818x; 1.0039x over previous
//
#include <hip/hip_runtime.h>

typedef unsigned short u16;
typedef short bf16x8 __attribute__((ext_vector_type(8)));   // 8 bf16 (4 VGPRs)
typedef float f32x4 __attribute__((ext_vector_type(4)));
typedef unsigned short us8 __attribute__((ext_vector_type(8)));
typedef unsigned long long u64;

__device__ __forceinline__ float bf2f(u16 u) {
  return __uint_as_float(((unsigned)u) << 16);
}
__device__ __forceinline__ u16 f2bf(float f) {
  unsigned u = __float_as_uint(f);
  u += 0x7fffu + ((u >> 16) & 1u);  // RNE (no NaNs in this workload)
  return (u16)(u >> 16);
}
__device__ __forceinline__ float rlf(float v, int l) {
  return __uint_as_float((unsigned)__builtin_amdgcn_readlane(__float_as_int(v), l));
}

// ---------------------------------------------------------------------------
// B=128, N=500. Stage A/B rows = 64000; stage C rows padded to 1024/batch.
// External buffers fp32; ws intermediates bf16.
// ---------------------------------------------------------------------------
#define M_AB 64000
#define M_C 131072

// ws layout (bytes), peak ~152.1 MB:
// arena A @ 0          : feat -> l2 -> l4 -> l6 (max 49,152,000)
// arena B @ 49,152,000 : l1 -> l3 -> l5 -> l7  (max 100,663,296)
#define OFF_ARENA_B 49152000u
#define OFF_IDX1 149815296u   // 128x500  int
#define OFF_IDX2 150071296u   // 128x1000 int
#define OFF_WB   150583296u   // bf16 weight arena (K padded)
// weight sub-offsets (bytes from OFF_WB); all 16B-aligned
#define WB1   0u        // 64 x 32    =   4,096
#define WB2   4096u     // 256 x 64   =  32,768
#define WBP1  36864u    // 256 x 256  = 131,072
#define WB3   167936u   // 256 x 288  = 147,456
#define WB4   315392u   // 384 x 256  = 196,608
#define WBP2  512000u   // 384 x 384  = 294,912
#define WB5   806912u   // 384 x 416  = 319,488
#define WB6   1126400u  // 512 x 384  = 393,216

// ---------------------------------------------------------------------------
// prep: all weight converts (fp32->bf16, K-padded) + zero(outf) + feat rows
// ---------------------------------------------------------------------------
struct PrepArgs {
  const float* wsrc[8];
  u16* wdst[8];
  int wN[8], wK[8], wKp[8];
  int wstart[9];  // cumulative element offsets; wstart[8] = total
};

__global__ __launch_bounds__(256) void prep_kernel(PrepArgs pa,
                                                   const float* __restrict__ x,
                                                   const float* __restrict__ cW,
                                                   const float* __restrict__ cb,
                                                   u16* __restrict__ feat,
                                                   float* __restrict__ outf) {
  int i = blockIdx.x * 256 + threadIdx.x;
  int S = pa.wstart[8];
  if (i < S) {
    int w = 0;
#pragma unroll
    for (int j = 1; j < 8; ++j)
      if (i >= pa.wstart[j]) w = j;
    int local = i - pa.wstart[w];
    int Kp = pa.wKp[w];
    int n = local / Kp, k = local - n * Kp;
    pa.wdst[w][local] = (k < pa.wK[w]) ? f2bf(pa.wsrc[w][n * pa.wK[w] + k]) : (u16)0;
  } else if (i < S + 65536) {
    outf[i - S] = 0.f;
  } else {
    int r = i - S - 65536;
    if (r < M_AB) {
      float x0 = x[r * 3], x1 = x[r * 3 + 1], x2 = x[r * 3 + 2];
      float z = x0 * cW[0] + x1 * cW[1] + x2 * cW[2] + cb[0];
      float conf = 1.0f / (1.0f + expf(-z));
      feat[r * 4 + 0] = f2bf(conf);
      feat[r * 4 + 1] = f2bf(x0);
      feat[r * 4 + 2] = f2bf(x1);
      feat[r * 4 + 3] = f2bf(x2);
    }
  }
}

// ---------------------------------------------------------------------------
// FPS wave body. Exact fp32 (_rn ops, np sum order ((dx2+dy2)+dz2)).
// Argmax: f32 v_max DPP reduce (row_shr 1,2,4,8 + row_bcast 15,31 -> lane63),
// then ==max compare -> ballot -> first set lane -> readlane local slot.
// First-set-lane + smallest-slot == np.argmax first-max tie-break.
// Invalid slots (p>=500) duplicate point 0: may tie, never precede lane 0.
// Centroid broadcast via readlane switch (no LDS on critical path).
// Early exit when max dist == 0 (all 500 selected): argmax(0s) = 0 forever.
// ---------------------------------------------------------------------------
template <int CTRL>
__device__ __forceinline__ float dppmaxf(float v) {
  int s = __builtin_amdgcn_update_dpp(0, __float_as_int(v), CTRL, 0xF, 0xF, true);
  return fmaxf(v, __uint_as_float((unsigned)s));
}

__device__ void fps_wave(const float4* cpt, int* out, int npoint, int fidx,
                         int lane) {
  float px[8], py[8], pz[8], dist[8];
  int base = lane * 8;
#pragma unroll
  for (int j = 0; j < 8; ++j) {
    int p = base + j;
    float4 c = cpt[p < 500 ? p : 0];  // invalid slots duplicate point 0
    px[j] = c.x; py[j] = c.y; pz[j] = c.z;
    dist[j] = 1e10f;
  }

  for (int t = 0; t < npoint; ++t) {
    if (lane == 0) out[t] = fidx;
    if (t == npoint - 1) break;
    // centroid via register broadcast (fidx uniform)
    int lo = fidx >> 3, sl = fidx & 7;
    float cx, cy, cz;
    switch (sl) {
#define FPS_CASE(J) \
  case J: cx = rlf(px[J], lo); cy = rlf(py[J], lo); cz = rlf(pz[J], lo); break;
      FPS_CASE(0) FPS_CASE(1) FPS_CASE(2) FPS_CASE(3)
      FPS_CASE(4) FPS_CASE(5) FPS_CASE(6) FPS_CASE(7)
#undef FPS_CASE
      default: cx = cy = cz = 0.f; break;
    }
#pragma unroll
    for (int j = 0; j < 8; ++j) {
      float dx = __fsub_rn(px[j], cx);
      float dy = __fsub_rn(py[j], cy);
      float dz = __fsub_rn(pz[j], cz);
      float d = __fadd_rn(__fadd_rn(__fmul_rn(dx, dx), __fmul_rn(dy, dy)),
                          __fmul_rn(dz, dz));
      dist[j] = fminf(dist[j], d);
    }
    // local tree max (f32; all dists >= 0)
    float m01 = fmaxf(dist[0], dist[1]), m23 = fmaxf(dist[2], dist[3]);
    float m45 = fmaxf(dist[4], dist[5]), m67 = fmaxf(dist[6], dist[7]);
    float lm = fmaxf(fmaxf(m01, m23), fmaxf(m45, m67));
    // wave reduce (bound_ctrl fills 0, safe for max of non-negatives)
    lm = dppmaxf<0x111>(lm);
    lm = dppmaxf<0x112>(lm);
    lm = dppmaxf<0x114>(lm);
    lm = dppmaxf<0x118>(lm);
    lm = dppmaxf<0x142>(lm);
    lm = dppmaxf<0x143>(lm);
    unsigned mb = (unsigned)__builtin_amdgcn_readlane(__float_as_int(lm), 63);
    if (mb == 0u) {  // all points selected; rest of argmaxes are index 0
      for (int tt = t + 1 + lane; tt < npoint; tt += 64) out[tt] = 0;
      break;
    }
    float mf = __uint_as_float(mb);
    // smallest local slot with dist == max (exact bit-compare; v_max returns
    // an input bit-exactly, all values +0-or-positive)
    int sel = 8;
#pragma unroll
    for (int j = 7; j >= 0; --j) sel = (dist[j] == mf) ? j : sel;
    u64 mask = __ballot(sel != 8);
    int li = (int)__ffsll(mask) - 1;  // smallest lane = smallest point range
    int sw = __builtin_amdgcn_readlane(sel, li);
    fidx = li * 8 + sw;
  }
}

// ---------------------------------------------------------------------------
// MFMA GEMM body: C = act(A' @ Wb^T + bias). 128x128 tile, BK=32, 4 waves,
// each wave 64x64 via 4x4 grid of 16x16x32 MFMAs.
// mode: 0 plain; 1 stage-B gather (b=r/500); 2 stage-C gather (b=r>>10,
//       p=r&1023, p>=1000 -> zero row). act: 0 none, 1 relu,
//       2 relu + per-batch col max -> atomicMax(outf) [1024 rows/batch].
// ---------------------------------------------------------------------------
#define LDT 40  // LDS row stride elems (80 B): 2-way bank alias = free
#define SMEM_BYTES (2 * 128 * LDT * 2 + 2 * 128 * 4)  // 21,504 B

__device__ __forceinline__ void gemm_body(
    const u16* __restrict__ A, int lda, const float* __restrict__ X,
    const int* __restrict__ idx, int mode, const u16* __restrict__ Wb,
    int ldw, const float* __restrict__ bias, u16* __restrict__ C, int ldc,
    int M, int K, int Kp, int N, int act, float* __restrict__ outf, int bx,
    int by, char* smem, int t) {
  u16* lA = (u16*)smem;
  u16* lB = (u16*)(smem + 128 * LDT * 2);
  float* red = (float*)(smem + 2 * 128 * LDT * 2);  // [2][128]

  const int m0 = bx * 128;
  const int n0 = by * 128;
  const int w = t >> 6;
  const int lane = t & 63;
  const int mrow = lane & 15;
  const int quad = lane >> 4;
  const int wm = w >> 1;
  const int wn = w & 1;

  const int crow = t >> 2;
  const int kc = (t & 3) * 8;

  const u16* aptr[2];
  const float* xptr[2] = {nullptr, nullptr};
  bool valid[2] = {true, true};
#pragma unroll
  for (int h = 0; h < 2; ++h) {
    int gr = m0 + crow + h * 64;
    if (mode == 0) {
      aptr[h] = A + (size_t)gr * lda;
    } else if (mode == 1) {
      int b = gr / 500;
      int p = gr - b * 500;
      int s = idx[b * 500 + p];
      size_t sr = (size_t)b * 500 + s;
      aptr[h] = A + sr * lda;
      xptr[h] = X + sr * 3;
    } else {
      int b = gr >> 10;
      int p = gr & 1023;
      valid[h] = (p < 1000);
      int s = valid[h] ? idx[b * 1000 + p] : 0;
      size_t sr = (size_t)b * 500 + s;
      aptr[h] = A + sr * lda;
      xptr[h] = X + sr * 3;
    }
  }
  const u16* wptr[2];
  bool wvalid[2];
#pragma unroll
  for (int h = 0; h < 2; ++h) {
    int wr = n0 + crow + h * 64;
    wvalid[h] = (wr < N);
    wptr[h] = Wb + (size_t)(wvalid[h] ? wr : 0) * ldw;
  }

  f32x4 acc[4][4];
  const f32x4 fz = {0.f, 0.f, 0.f, 0.f};
#pragma unroll
  for (int i = 0; i < 4; ++i)
#pragma unroll
    for (int j = 0; j < 4; ++j) acc[i][j] = fz;

  for (int k0 = 0; k0 < Kp; k0 += 32) {
    __syncthreads();
    int kk = k0 + kc;
#pragma unroll
    for (int h = 0; h < 2; ++h) {
      us8 va;
      if (mode == 0) {
        if (kk + 8 <= K) {
          va = *(const us8*)(aptr[h] + kk);
        } else {
#pragma unroll
          for (int j = 0; j < 8; ++j)
            va[j] = (kk + j < K) ? aptr[h][kk + j] : (u16)0;
        }
      } else {
        if (valid[h] && kk + 8 <= lda) {
          va = *(const us8*)(aptr[h] + kk);
        } else {
#pragma unroll
          for (int j = 0; j < 8; ++j) {
            int k = kk + j;
            u16 v = 0;
            if (valid[h]) {
              if (k < lda) v = aptr[h][k];
              else if (k < lda + 3) v = f2bf(xptr[h][k - lda]);
            }
            va[j] = v;
          }
        }
      }
      *(us8*)(lA + (crow + h * 64) * LDT + kc) = va;
      us8 vb = {0, 0, 0, 0, 0, 0, 0, 0};
      if (wvalid[h]) vb = *(const us8*)(wptr[h] + kk);
      *(us8*)(lB + (crow + h * 64) * LDT + kc) = vb;
    }
    __syncthreads();

    const u16* aBase = lA + (wm * 64 + mrow) * LDT + quad * 8;
    const u16* bBase = lB + (wn * 64 + mrow) * LDT + quad * 8;
    bf16x8 af[4], bfv[4];
#pragma unroll
    for (int mi = 0; mi < 4; ++mi) af[mi] = *(const bf16x8*)(aBase + mi * 16 * LDT);
#pragma unroll
    for (int ni = 0; ni < 4; ++ni) bfv[ni] = *(const bf16x8*)(bBase + ni * 16 * LDT);
#pragma unroll
    for (int mi = 0; mi < 4; ++mi)
#pragma unroll
      for (int ni = 0; ni < 4; ++ni)
        acc[mi][ni] = __builtin_amdgcn_mfma_f32_16x16x32_bf16(
            af[mi], bfv[ni], acc[mi][ni], 0, 0, 0);
  }

  if (act < 2) {
#pragma unroll
    for (int ni = 0; ni < 4; ++ni) {
      int col = n0 + wn * 64 + ni * 16 + mrow;
      if (col >= N) continue;
      float bv = bias[col];
#pragma unroll
      for (int mi = 0; mi < 4; ++mi)
#pragma unroll
        for (int r = 0; r < 4; ++r) {
          int grow = m0 + wm * 64 + mi * 16 + quad * 4 + r;
          float v = acc[mi][ni][r] + bv;
          if (act == 1) v = fmaxf(v, 0.f);
          C[(size_t)grow * ldc + col] = f2bf(v);
        }
    }
  } else {
#pragma unroll
    for (int ni = 0; ni < 4; ++ni) {
      int col = n0 + wn * 64 + ni * 16 + mrow;
      float bv = (col < N) ? bias[col] : 0.f;
      float mx = 0.f;
#pragma unroll
      for (int mi = 0; mi < 4; ++mi)
#pragma unroll
        for (int r = 0; r < 4; ++r) {
          int grow = m0 + wm * 64 + mi * 16 + quad * 4 + r;
          float v = fmaxf(acc[mi][ni][r] + bv, 0.f);
          if ((grow & 1023) < 1000) mx = fmaxf(mx, v);
        }
      mx = fmaxf(mx, __shfl_xor(mx, 16, 64));
      mx = fmaxf(mx, __shfl_xor(mx, 32, 64));
      if (quad == 0) red[wm * 128 + wn * 64 + ni * 16 + mrow] = mx;
    }
    __syncthreads();
    if (t < 128) {
      int col = n0 + t;
      if (col < N) {
        float m = fmaxf(red[t], red[128 + t]);
        int b = m0 >> 10;
        atomicMax((unsigned*)&outf[b * 512 + col], __float_as_uint(m));
      }
    }
  }
}

__global__ __launch_bounds__(256) void gemm_mfma(
    const u16* __restrict__ A, int lda, const float* __restrict__ X,
    const int* __restrict__ idx, int mode, const u16* __restrict__ Wb,
    int ldw, const float* __restrict__ bias, u16* __restrict__ C, int ldc,
    int M, int K, int Kp, int N, int act, float* __restrict__ outf) {
  __shared__ __align__(16) char smem[SMEM_BYTES];
  gemm_body(A, lda, X, idx, mode, Wb, ldw, bias, C, ldc, M, K, Kp, N, act,
            outf, blockIdx.x, blockIdx.y, smem, threadIdx.x);
}

// ---------------------------------------------------------------------------
// Fused: blocks [0,1000) = stage-A GEMM3 (l2 @ pc1 -> l3, 64000x256x256);
//        blocks [1000,1256) = FPS (independent of GEMM3; hidden under it)
// ---------------------------------------------------------------------------
__global__ __launch_bounds__(256) void gemm3_fps_kernel(
    const u16* __restrict__ A, const u16* __restrict__ Wb,
    const float* __restrict__ bias, u16* __restrict__ C,
    const float* __restrict__ x, const int* __restrict__ init1,
    const int* __restrict__ init2, int* __restrict__ idx1,
    int* __restrict__ idx2) {
  __shared__ __align__(16) char smem[SMEM_BYTES];
  int bid = blockIdx.x;
  int t = threadIdx.x;
  if (bid < 1000) {
    int by = bid / 500, bx = bid - by * 500;
    gemm_body(A, 256, nullptr, nullptr, 0, Wb, 256, bias, C, 256, M_AB, 256,
              256, 256, 0, nullptr, bx, by, smem, t);
  } else {
    int bb = bid - 1000;
    int b = bb & 127;
    bool second = bb >= 128;
    float4* cpt = (float4*)smem;
    const float* xb = x + (size_t)b * 1500;
    for (int p = t; p < 500; p += 256)
      cpt[p] = make_float4(xb[p * 3], xb[p * 3 + 1], xb[p * 3 + 2], 0.f);
    __syncthreads();
    if (t < 64) {
      fps_wave(cpt, second ? (idx2 + b * 1000) : (idx1 + b * 500),
               second ? 1000 : 500, second ? init2[b] : init1[b], t);
    }
  }
}

// ---------------------------------------------------------------------------
extern "C" void kernel_launch(void* const* d_in, const int* in_sizes, int n_in,
                              void* d_out, int out_size, void* d_ws,
                              size_t ws_size, hipStream_t stream) {
  const float* x      = (const float*)d_in[0];
  const float* conf_W = (const float*)d_in[1];
  const float* conf_b = (const float*)d_in[2];
  const float* w1     = (const float*)d_in[3];
  const float* b1     = (const float*)d_in[4];
  const float* w2     = (const float*)d_in[5];
  const float* b2     = (const float*)d_in[6];
  const float* pc1_W  = (const float*)d_in[7];
  const float* pc1_b  = (const float*)d_in[8];
  const float* w3     = (const float*)d_in[9];
  const float* b3     = (const float*)d_in[10];
  const float* w4     = (const float*)d_in[11];
  const float* b4     = (const float*)d_in[12];
  const float* pc2_W  = (const float*)d_in[13];
  const float* pc2_b  = (const float*)d_in[14];
  const float* w5     = (const float*)d_in[15];
  const float* b5     = (const float*)d_in[16];
  const float* w6     = (const float*)d_in[17];
  const float* b6     = (const float*)d_in[18];
  const int* init1    = (const int*)d_in[20];
  const int* init2    = (const int*)d_in[21];

  char* ws = (char*)d_ws;
  u16* feat = (u16*)(ws + 0);
  u16* l2b  = (u16*)(ws + 0);
  u16* l4b  = (u16*)(ws + 0);
  u16* l6b  = (u16*)(ws + 0);
  u16* l1b  = (u16*)(ws + OFF_ARENA_B);
  u16* l3b  = (u16*)(ws + OFF_ARENA_B);
  u16* l5b  = (u16*)(ws + OFF_ARENA_B);
  u16* l7b  = (u16*)(ws + OFF_ARENA_B);
  int* idx1 = (int*)(ws + OFF_IDX1);
  int* idx2 = (int*)(ws + OFF_IDX2);
  u16* wb   = (u16*)(ws + OFF_WB);
  u16* wb1  = wb + WB1 / 2;
  u16* wb2  = wb + WB2 / 2;
  u16* wbp1 = wb + WBP1 / 2;
  u16* wb3  = wb + WB3 / 2;
  u16* wb4  = wb + WB4 / 2;
  u16* wbp2 = wb + WBP2 / 2;
  u16* wb5  = wb + WB5 / 2;
  u16* wb6  = wb + WB6 / 2;
  float* outf = (float*)d_out;  // 128x512 fp32 accumulated via atomicMax

  // ---- prep: 8 weight converts + zero(outf) + feat, one dispatch
  PrepArgs pa;
  const float* srcs[8] = {w1, w2, pc1_W, w3, w4, pc2_W, w5, w6};
  u16* dsts[8] = {wb1, wb2, wbp1, wb3, wb4, wbp2, wb5, wb6};
  int Ns[8]  = {64, 256, 256, 256, 384, 384, 384, 512};
  int Ks[8]  = {4, 64, 256, 259, 256, 384, 387, 384};
  int Kps[8] = {32, 64, 256, 288, 256, 384, 416, 384};
  int cum = 0;
  for (int i = 0; i < 8; ++i) {
    pa.wsrc[i] = srcs[i];
    pa.wdst[i] = dsts[i];
    pa.wN[i] = Ns[i];
    pa.wK[i] = Ks[i];
    pa.wKp[i] = Kps[i];
    pa.wstart[i] = cum;
    cum += Ns[i] * Kps[i];
  }
  pa.wstart[8] = cum;  // 759,808
  int total = cum + 65536 + M_AB;  // + zero + feat = 889,344
  prep_kernel<<<(total + 255) / 256, 256, 0, stream>>>(pa, x, conf_W, conf_b,
                                                       feat, outf);

  // stage A
  gemm_mfma<<<dim3(500, 1), 256, 0, stream>>>(feat, 4, nullptr, nullptr, 0,
      wb1, 32, b1, l1b, 64, M_AB, 4, 32, 64, 1, nullptr);
  gemm_mfma<<<dim3(500, 2), 256, 0, stream>>>(l1b, 64, nullptr, nullptr, 0,
      wb2, 64, b2, l2b, 256, M_AB, 64, 64, 256, 1, nullptr);
  // stage A GEMM3 + FPS fused (FPS result first needed by next dispatch)
  gemm3_fps_kernel<<<1256, 256, 0, stream>>>(l2b, wbp1, pc1_b, l3b, x, init1,
                                             init2, idx1, idx2);
  // stage B (gather fused, mode 1)
  gemm_mfma<<<dim3(500, 2), 256, 0, stream>>>(l3b, 256, x, idx1, 1,
      wb3, 288, b3, l4b, 256, M_AB, 259, 288, 256, 1, nullptr);
  gemm_mfma<<<dim3(500, 3), 256, 0, stream>>>(l4b, 256, nullptr, nullptr, 0,
      wb4, 256, b4, l5b, 384, M_AB, 256, 256, 384, 1, nullptr);
  gemm_mfma<<<dim3(500, 3), 256, 0, stream>>>(l5b, 384, nullptr, nullptr, 0,
      wbp2, 384, pc2_b, l6b, 384, M_AB, 384, 384, 384, 0, nullptr);
  // stage C (gather fused, mode 2; rows padded to 1024/batch)
  gemm_mfma<<<dim3(1024, 3), 256, 0, stream>>>(l6b, 384, x, idx2, 2,
      wb5, 416, b5, l7b, 384, M_C, 387, 416, 384, 1, nullptr);
  gemm_mfma<<<dim3(1024, 4), 256, 0, stream>>>(l7b, 384, nullptr, nullptr, 0,
      wb6, 384, b6, nullptr, 0, M_C, 384, 384, 512, 2, outf);
}

// Round 8
// 625.385 us; speedup vs baseline: 8.9938x; 1.3262x over previous
//
#include <hip/hip_runtime.h>

typedef unsigned short u16;
typedef short bf16x8 __attribute__((ext_vector_type(8)));   // 8 bf16 (4 VGPRs)
typedef float f32x4 __attribute__((ext_vector_type(4)));
typedef unsigned short us8 __attribute__((ext_vector_type(8)));
typedef unsigned long long u64;

__device__ __forceinline__ float bf2f(u16 u) {
  return __uint_as_float(((unsigned)u) << 16);
}
__device__ __forceinline__ u16 f2bf(float f) {
  unsigned u = __float_as_uint(f);
  u += 0x7fffu + ((u >> 16) & 1u);  // RNE (no NaNs in this workload)
  return (u16)(u >> 16);
}
__device__ __forceinline__ float rlf(float v, int l) {
  return __uint_as_float((unsigned)__builtin_amdgcn_readlane(__float_as_int(v), l));
}

// ---------------------------------------------------------------------------
// B=128, N=500. Stage A/B rows = 64000. Stage C: all 500 rows/batch directly
// (fps2 eliminated: its gather set == all rows, max-pool is order/dup
// invariant), padded to 512/batch -> M_C = 65536.
// ---------------------------------------------------------------------------
#define M_AB 64000
#define M_C 65536

// ws layout (bytes):
// arena A @ 0          : feat -> l2 -> l4 -> l6 (max 49,152,000)
// arena B @ 49,152,000 : l1 -> l3 -> l5 -> l7  (max 100,663,296)
#define OFF_ARENA_B 49152000u
#define OFF_IDX1 149815296u   // 128x500 int
#define OFF_FPSD 150071296u   // fps dist state: 128*64*8 floats = 262,144 B
#define OFF_FPSI 150333440u   // fps fidx state: 128 int
#define OFF_WB   150583296u   // bf16 weight arena (K padded)
#define WB1   0u        // 64 x 32
#define WB2   4096u     // 256 x 64
#define WBP1  36864u    // 256 x 256
#define WB3   167936u   // 256 x 288
#define WB4   315392u   // 384 x 256
#define WBP2  512000u   // 384 x 384
#define WB5   806912u   // 384 x 416
#define WB6   1126400u  // 512 x 384

// ---------------------------------------------------------------------------
// FPS segment: iterations [t0, t0+tcnt) of the sequential chain for batch b.
// Exact fp32 (_rn ops, np sum order), np.argmax first-max tie-break via
// f32 DPP max reduce + ballot/ffs (smallest lane, smallest slot).
// State (dist[8]/lane, fidx) persisted in ws between segments.
// ---------------------------------------------------------------------------
template <int CTRL>
__device__ __forceinline__ float dppmaxf(float v) {
  int s = __builtin_amdgcn_update_dpp(0, __float_as_int(v), CTRL, 0xF, 0xF, true);
  return fmaxf(v, __uint_as_float((unsigned)s));
}

__device__ void fps_seg(const float4* cpt, int* out, const int* init1,
                        float* dstate, int* fstate, int b, int t0, int tcnt,
                        int lane) {
  float px[8], py[8], pz[8], dist[8];
  int base = lane * 8;
#pragma unroll
  for (int j = 0; j < 8; ++j) {
    int p = base + j;
    float4 c = cpt[p < 500 ? p : 0];  // invalid slots duplicate point 0
    px[j] = c.x; py[j] = c.y; pz[j] = c.z;
  }
  int fidx;
  if (t0 == 0) {
#pragma unroll
    for (int j = 0; j < 8; ++j) dist[j] = 1e10f;
    fidx = init1[b];
  } else {
#pragma unroll
    for (int j = 0; j < 8; ++j) dist[j] = dstate[(b * 64 + lane) * 8 + j];
    fidx = fstate[b];
  }

  int tend = t0 + tcnt;
  for (int t = t0; t < tend; ++t) {
    if (lane == 0) out[t] = fidx;
    if (t == 499) return;  // final emission done; no state needed
    // centroid via register broadcast (fidx uniform)
    int lo = fidx >> 3, sl = fidx & 7;
    float cx, cy, cz;
    switch (sl) {
#define FPS_CASE(J) \
  case J: cx = rlf(px[J], lo); cy = rlf(py[J], lo); cz = rlf(pz[J], lo); break;
      FPS_CASE(0) FPS_CASE(1) FPS_CASE(2) FPS_CASE(3)
      FPS_CASE(4) FPS_CASE(5) FPS_CASE(6) FPS_CASE(7)
#undef FPS_CASE
      default: cx = cy = cz = 0.f; break;
    }
#pragma unroll
    for (int j = 0; j < 8; ++j) {
      float dx = __fsub_rn(px[j], cx);
      float dy = __fsub_rn(py[j], cy);
      float dz = __fsub_rn(pz[j], cz);
      float d = __fadd_rn(__fadd_rn(__fmul_rn(dx, dx), __fmul_rn(dy, dy)),
                          __fmul_rn(dz, dz));
      dist[j] = fminf(dist[j], d);
    }
    float m01 = fmaxf(dist[0], dist[1]), m23 = fmaxf(dist[2], dist[3]);
    float m45 = fmaxf(dist[4], dist[5]), m67 = fmaxf(dist[6], dist[7]);
    float lm = fmaxf(fmaxf(m01, m23), fmaxf(m45, m67));
    lm = dppmaxf<0x111>(lm);
    lm = dppmaxf<0x112>(lm);
    lm = dppmaxf<0x114>(lm);
    lm = dppmaxf<0x118>(lm);
    lm = dppmaxf<0x142>(lm);
    lm = dppmaxf<0x143>(lm);
    float mf = rlf(lm, 63);
    // smallest slot with dist == max (bit-exact: v_max returns an input)
    int sel = 8;
#pragma unroll
    for (int j = 7; j >= 0; --j) sel = (dist[j] == mf) ? j : sel;
    u64 mask = __ballot(sel != 8);
    int li = (int)__ffsll(mask) - 1;  // smallest lane = smallest point range
    int sw = __builtin_amdgcn_readlane(sel, li);
    fidx = li * 8 + sw;
    // all-zero dist (all points selected) naturally yields fidx = 0 = np.argmax
  }
  // save state for next segment
#pragma unroll
  for (int j = 0; j < 8; ++j) dstate[(b * 64 + lane) * 8 + j] = dist[j];
  if (lane == 0) fstate[b] = fidx;
}

// ---------------------------------------------------------------------------
// MFMA GEMM body: C = act(A' @ Wb^T + bias). 128x128 tile, BK=32, 4 waves,
// each wave 64x64 via 4x4 grid of 16x16x32 MFMAs.
// mode: 0 plain; 1 stage-B gather (b=r/500, idx row); 3 stage-C direct concat
//       (b=r>>9, p=r&511, p>=500 -> zero row; src row b*500+p, concat x)
// act: 0 none, 1 relu, 2 relu + per-batch col max -> atomicMax(outf)
//      [stage C: 512 rows/batch, rows with (r&511)>=500 masked]
// ---------------------------------------------------------------------------
#define LDT 40  // LDS row stride elems (80 B): 2-way bank alias = free
#define SMEM_BYTES (2 * 128 * LDT * 2 + 2 * 128 * 4)  // 21,504 B

__device__ __forceinline__ void gemm_body(
    const u16* __restrict__ A, int lda, const float* __restrict__ X,
    const int* __restrict__ idx, int mode, const u16* __restrict__ Wb,
    int ldw, const float* __restrict__ bias, u16* __restrict__ C, int ldc,
    int M, int K, int Kp, int N, int act, float* __restrict__ outf, int bx,
    int by, char* smem, int t) {
  u16* lA = (u16*)smem;
  u16* lB = (u16*)(smem + 128 * LDT * 2);
  float* red = (float*)(smem + 2 * 128 * LDT * 2);  // [2][128]

  const int m0 = bx * 128;
  const int n0 = by * 128;
  const int w = t >> 6;
  const int lane = t & 63;
  const int mrow = lane & 15;
  const int quad = lane >> 4;
  const int wm = w >> 1;
  const int wn = w & 1;

  const int crow = t >> 2;
  const int kc = (t & 3) * 8;

  const u16* aptr[2];
  const float* xptr[2] = {nullptr, nullptr};
  bool valid[2] = {true, true};
#pragma unroll
  for (int h = 0; h < 2; ++h) {
    int gr = m0 + crow + h * 64;
    if (mode == 0) {
      aptr[h] = A + (size_t)gr * lda;
    } else if (mode == 1) {
      int b = gr / 500;
      int p = gr - b * 500;
      int s = idx[b * 500 + p];
      size_t sr = (size_t)b * 500 + s;
      aptr[h] = A + sr * lda;
      xptr[h] = X + sr * 3;
    } else {  // mode 3: direct padded concat
      int b = gr >> 9;
      int p = gr & 511;
      valid[h] = (p < 500);
      size_t sr = (size_t)b * 500 + (valid[h] ? p : 0);
      aptr[h] = A + sr * lda;
      xptr[h] = X + sr * 3;
    }
  }
  const u16* wptr[2];
  bool wvalid[2];
#pragma unroll
  for (int h = 0; h < 2; ++h) {
    int wr = n0 + crow + h * 64;
    wvalid[h] = (wr < N);
    wptr[h] = Wb + (size_t)(wvalid[h] ? wr : 0) * ldw;
  }

  f32x4 acc[4][4];
  const f32x4 fz = {0.f, 0.f, 0.f, 0.f};
#pragma unroll
  for (int i = 0; i < 4; ++i)
#pragma unroll
    for (int j = 0; j < 4; ++j) acc[i][j] = fz;

  for (int k0 = 0; k0 < Kp; k0 += 32) {
    __syncthreads();
    int kk = k0 + kc;
#pragma unroll
    for (int h = 0; h < 2; ++h) {
      us8 va;
      if (mode == 0) {
        if (kk + 8 <= K) {
          va = *(const us8*)(aptr[h] + kk);
        } else {
#pragma unroll
          for (int j = 0; j < 8; ++j)
            va[j] = (kk + j < K) ? aptr[h][kk + j] : (u16)0;
        }
      } else {
        if (valid[h] && kk + 8 <= lda) {
          va = *(const us8*)(aptr[h] + kk);
        } else {
#pragma unroll
          for (int j = 0; j < 8; ++j) {
            int k = kk + j;
            u16 v = 0;
            if (valid[h]) {
              if (k < lda) v = aptr[h][k];
              else if (k < lda + 3) v = f2bf(xptr[h][k - lda]);
            }
            va[j] = v;
          }
        }
      }
      *(us8*)(lA + (crow + h * 64) * LDT + kc) = va;
      us8 vb = {0, 0, 0, 0, 0, 0, 0, 0};
      if (wvalid[h]) vb = *(const us8*)(wptr[h] + kk);
      *(us8*)(lB + (crow + h * 64) * LDT + kc) = vb;
    }
    __syncthreads();

    const u16* aBase = lA + (wm * 64 + mrow) * LDT + quad * 8;
    const u16* bBase = lB + (wn * 64 + mrow) * LDT + quad * 8;
    bf16x8 af[4], bfv[4];
#pragma unroll
    for (int mi = 0; mi < 4; ++mi) af[mi] = *(const bf16x8*)(aBase + mi * 16 * LDT);
#pragma unroll
    for (int ni = 0; ni < 4; ++ni) bfv[ni] = *(const bf16x8*)(bBase + ni * 16 * LDT);
#pragma unroll
    for (int mi = 0; mi < 4; ++mi)
#pragma unroll
      for (int ni = 0; ni < 4; ++ni)
        acc[mi][ni] = __builtin_amdgcn_mfma_f32_16x16x32_bf16(
            af[mi], bfv[ni], acc[mi][ni], 0, 0, 0);
  }

  if (act < 2) {
#pragma unroll
    for (int ni = 0; ni < 4; ++ni) {
      int col = n0 + wn * 64 + ni * 16 + mrow;
      if (col >= N) continue;
      float bv = bias[col];
#pragma unroll
      for (int mi = 0; mi < 4; ++mi)
#pragma unroll
        for (int r = 0; r < 4; ++r) {
          int grow = m0 + wm * 64 + mi * 16 + quad * 4 + r;
          float v = acc[mi][ni][r] + bv;
          if (act == 1) v = fmaxf(v, 0.f);
          C[(size_t)grow * ldc + col] = f2bf(v);
        }
    }
  } else {
#pragma unroll
    for (int ni = 0; ni < 4; ++ni) {
      int col = n0 + wn * 64 + ni * 16 + mrow;
      float bv = (col < N) ? bias[col] : 0.f;
      float mx = 0.f;
#pragma unroll
      for (int mi = 0; mi < 4; ++mi)
#pragma unroll
        for (int r = 0; r < 4; ++r) {
          int grow = m0 + wm * 64 + mi * 16 + quad * 4 + r;
          float v = fmaxf(acc[mi][ni][r] + bv, 0.f);
          if ((grow & 511) < 500) mx = fmaxf(mx, v);
        }
      mx = fmaxf(mx, __shfl_xor(mx, 16, 64));
      mx = fmaxf(mx, __shfl_xor(mx, 32, 64));
      if (quad == 0) red[wm * 128 + wn * 64 + ni * 16 + mrow] = mx;
    }
    __syncthreads();
    if (t < 128) {
      int col = n0 + t;
      if (col < N) {
        float m = fmaxf(red[t], red[128 + t]);
        int b = m0 >> 9;
        atomicMax((unsigned*)&outf[b * 512 + col], __float_as_uint(m));
      }
    }
  }
}

// plain GEMM kernel (stages B, C)
__global__ __launch_bounds__(256) void gemm_mfma(
    const u16* __restrict__ A, int lda, const float* __restrict__ X,
    const int* __restrict__ idx, int mode, const u16* __restrict__ Wb,
    int ldw, const float* __restrict__ bias, u16* __restrict__ C, int ldc,
    int M, int K, int Kp, int N, int act, float* __restrict__ outf) {
  __shared__ __align__(16) char smem[SMEM_BYTES];
  gemm_body(A, lda, X, idx, mode, Wb, ldw, bias, C, ldc, M, K, Kp, N, act,
            outf, blockIdx.x, blockIdx.y, smem, threadIdx.x);
}

// GEMM + FPS segment fused; FPS blocks FIRST (0..127) so they start at t=0
__global__ __launch_bounds__(256) void gemm_fps(
    const u16* __restrict__ A, int lda, const u16* __restrict__ Wb, int ldw,
    const float* __restrict__ bias, u16* __restrict__ C, int ldc, int M,
    int K, int Kp, int N, int gx, const float* __restrict__ x,
    const int* __restrict__ init1, int* __restrict__ idx1,
    float* __restrict__ dstate, int* __restrict__ fstate, int t0, int tcnt) {
  __shared__ __align__(16) char smem[SMEM_BYTES];
  int bid = blockIdx.x;
  int t = threadIdx.x;
  if (bid < 128) {
    int b = bid;
    float4* cpt = (float4*)smem;
    const float* xb = x + (size_t)b * 1500;
    for (int p = t; p < 500; p += 256)
      cpt[p] = make_float4(xb[p * 3], xb[p * 3 + 1], xb[p * 3 + 2], 0.f);
    __syncthreads();
    if (t < 64)
      fps_seg(cpt, idx1 + b * 500, init1, dstate, fstate, b, t0, tcnt, t);
  } else {
    int g = bid - 128;
    int by = g / gx, bx = g - by * gx;
    gemm_body(A, lda, nullptr, nullptr, 0, Wb, ldw, bias, C, ldc, M, K, Kp, N,
              (K == 256 && N == 256) ? 0 : 1, nullptr, bx, by, smem, t);
  }
}

// ---------------------------------------------------------------------------
// prep (+ FPS segment 0): weight converts + zero(outf) + feat rows
// ---------------------------------------------------------------------------
struct PrepArgs {
  const float* wsrc[8];
  u16* wdst[8];
  int wN[8], wK[8], wKp[8];
  int wstart[9];
};

__global__ __launch_bounds__(256) void prep_kernel(
    PrepArgs pa, const float* __restrict__ x, const float* __restrict__ cW,
    const float* __restrict__ cb, u16* __restrict__ feat,
    float* __restrict__ outf, const int* __restrict__ init1,
    int* __restrict__ idx1, float* __restrict__ dstate,
    int* __restrict__ fstate) {
  __shared__ float4 cpt[512];
  int bid = blockIdx.x;
  int t = threadIdx.x;
  if (bid < 128) {
    int b = bid;
    const float* xb = x + (size_t)b * 1500;
    for (int p = t; p < 500; p += 256)
      cpt[p] = make_float4(xb[p * 3], xb[p * 3 + 1], xb[p * 3 + 2], 0.f);
    __syncthreads();
    if (t < 64) fps_seg(cpt, idx1 + b * 500, init1, dstate, fstate, b, 0, 125, t);
    return;
  }
  int i = (bid - 128) * 256 + t;
  int S = pa.wstart[8];
  if (i < S) {
    int w = 0;
#pragma unroll
    for (int j = 1; j < 8; ++j)
      if (i >= pa.wstart[j]) w = j;
    int local = i - pa.wstart[w];
    int Kp = pa.wKp[w];
    int n = local / Kp, k = local - n * Kp;
    pa.wdst[w][local] = (k < pa.wK[w]) ? f2bf(pa.wsrc[w][n * pa.wK[w] + k]) : (u16)0;
  } else if (i < S + 65536) {
    outf[i - S] = 0.f;
  } else {
    int r = i - S - 65536;
    if (r < M_AB) {
      float x0 = x[r * 3], x1 = x[r * 3 + 1], x2 = x[r * 3 + 2];
      float z = x0 * cW[0] + x1 * cW[1] + x2 * cW[2] + cb[0];
      float conf = 1.0f / (1.0f + expf(-z));
      feat[r * 4 + 0] = f2bf(conf);
      feat[r * 4 + 1] = f2bf(x0);
      feat[r * 4 + 2] = f2bf(x1);
      feat[r * 4 + 3] = f2bf(x2);
    }
  }
}

// ---------------------------------------------------------------------------
extern "C" void kernel_launch(void* const* d_in, const int* in_sizes, int n_in,
                              void* d_out, int out_size, void* d_ws,
                              size_t ws_size, hipStream_t stream) {
  const float* x      = (const float*)d_in[0];
  const float* conf_W = (const float*)d_in[1];
  const float* conf_b = (const float*)d_in[2];
  const float* w1     = (const float*)d_in[3];
  const float* b1     = (const float*)d_in[4];
  const float* w2     = (const float*)d_in[5];
  const float* b2     = (const float*)d_in[6];
  const float* pc1_W  = (const float*)d_in[7];
  const float* pc1_b  = (const float*)d_in[8];
  const float* w3     = (const float*)d_in[9];
  const float* b3     = (const float*)d_in[10];
  const float* w4     = (const float*)d_in[11];
  const float* b4     = (const float*)d_in[12];
  const float* pc2_W  = (const float*)d_in[13];
  const float* pc2_b  = (const float*)d_in[14];
  const float* w5     = (const float*)d_in[15];
  const float* b5     = (const float*)d_in[16];
  const float* w6     = (const float*)d_in[17];
  const float* b6     = (const float*)d_in[18];
  const int* init1    = (const int*)d_in[20];

  char* ws = (char*)d_ws;
  u16* feat = (u16*)(ws + 0);
  u16* l2b  = (u16*)(ws + 0);
  u16* l4b  = (u16*)(ws + 0);
  u16* l6b  = (u16*)(ws + 0);
  u16* l1b  = (u16*)(ws + OFF_ARENA_B);
  u16* l3b  = (u16*)(ws + OFF_ARENA_B);
  u16* l5b  = (u16*)(ws + OFF_ARENA_B);
  u16* l7b  = (u16*)(ws + OFF_ARENA_B);
  int* idx1 = (int*)(ws + OFF_IDX1);
  float* dstate = (float*)(ws + OFF_FPSD);
  int* fstate   = (int*)(ws + OFF_FPSI);
  u16* wb   = (u16*)(ws + OFF_WB);
  u16* wb1  = wb + WB1 / 2;
  u16* wb2  = wb + WB2 / 2;
  u16* wbp1 = wb + WBP1 / 2;
  u16* wb3  = wb + WB3 / 2;
  u16* wb4  = wb + WB4 / 2;
  u16* wbp2 = wb + WBP2 / 2;
  u16* wb5  = wb + WB5 / 2;
  u16* wb6  = wb + WB6 / 2;
  float* outf = (float*)d_out;  // 128x512 fp32 accumulated via atomicMax

  PrepArgs pa;
  const float* srcs[8] = {w1, w2, pc1_W, w3, w4, pc2_W, w5, w6};
  u16* dsts[8] = {wb1, wb2, wbp1, wb3, wb4, wbp2, wb5, wb6};
  int Ns[8]  = {64, 256, 256, 256, 384, 384, 384, 512};
  int Ks[8]  = {4, 64, 256, 259, 256, 384, 387, 384};
  int Kps[8] = {32, 64, 256, 288, 256, 384, 416, 384};
  int cum = 0;
  for (int i = 0; i < 8; ++i) {
    pa.wsrc[i] = srcs[i];
    pa.wdst[i] = dsts[i];
    pa.wN[i] = Ns[i];
    pa.wK[i] = Ks[i];
    pa.wKp[i] = Kps[i];
    pa.wstart[i] = cum;
    cum += Ns[i] * Kps[i];
  }
  pa.wstart[8] = cum;
  int total = cum + 65536 + M_AB;

  // prep + FPS seg0 (iters 0..124)
  prep_kernel<<<128 + (total + 255) / 256, 256, 0, stream>>>(
      pa, x, conf_W, conf_b, feat, outf, init1, idx1, dstate, fstate);
  // stage A + FPS segs 1..3 (FPS blocks first in each kernel)
  gemm_fps<<<128 + 500, 256, 0, stream>>>(feat, 4, wb1, 32, b1, l1b, 64, M_AB,
      4, 32, 64, 500, x, init1, idx1, dstate, fstate, 125, 125);
  gemm_fps<<<128 + 1000, 256, 0, stream>>>(l1b, 64, wb2, 64, b2, l2b, 256,
      M_AB, 64, 64, 256, 500, x, init1, idx1, dstate, fstate, 250, 125);
  gemm_fps<<<128 + 1000, 256, 0, stream>>>(l2b, 256, wbp1, 256, pc1_b, l3b,
      256, M_AB, 256, 256, 256, 500, x, init1, idx1, dstate, fstate, 375, 125);
  // stage B (gather fused, mode 1)
  gemm_mfma<<<dim3(500, 2), 256, 0, stream>>>(l3b, 256, x, idx1, 1,
      wb3, 288, b3, l4b, 256, M_AB, 259, 288, 256, 1, nullptr);
  gemm_mfma<<<dim3(500, 3), 256, 0, stream>>>(l4b, 256, nullptr, nullptr, 0,
      wb4, 256, b4, l5b, 384, M_AB, 256, 256, 384, 1, nullptr);
  gemm_mfma<<<dim3(500, 3), 256, 0, stream>>>(l5b, 384, nullptr, nullptr, 0,
      wbp2, 384, pc2_b, l6b, 384, M_AB, 384, 384, 384, 0, nullptr);
  // stage C (fps2 eliminated: direct concat over all 500 rows, pad 512/batch)
  gemm_mfma<<<dim3(512, 3), 256, 0, stream>>>(l6b, 384, x, nullptr, 3,
      wb5, 416, b5, l7b, 384, M_C, 387, 416, 384, 1, nullptr);
  gemm_mfma<<<dim3(512, 4), 256, 0, stream>>>(l7b, 384, nullptr, nullptr, 0,
      wb6, 384, b6, nullptr, 0, M_C, 384, 384, 512, 2, outf);
}

// Round 9
// 473.051 us; speedup vs baseline: 11.8900x; 1.3220x over previous
//
#include <hip/hip_runtime.h>

typedef unsigned short u16;
typedef short bf16x8 __attribute__((ext_vector_type(8)));   // 8 bf16 (4 VGPRs)
typedef float f32x4 __attribute__((ext_vector_type(4)));
typedef unsigned short us8 __attribute__((ext_vector_type(8)));
typedef unsigned long long u64;

__device__ __forceinline__ float bf2f(u16 u) {
  return __uint_as_float(((unsigned)u) << 16);
}
__device__ __forceinline__ u16 f2bf(float f) {
  unsigned u = __float_as_uint(f);
  u += 0x7fffu + ((u >> 16) & 1u);  // RNE (no NaNs in this workload)
  return (u16)(u >> 16);
}
__device__ __forceinline__ float rlf(float v, int l) {
  return __uint_as_float((unsigned)__builtin_amdgcn_readlane(__float_as_int(v), l));
}
// async global(16B/lane) -> LDS(wave-uniform base + lane*16) [m97-verified]
__device__ __forceinline__ void gload16(const u16* g, u16* l) {
  __builtin_amdgcn_global_load_lds(
      (const __attribute__((address_space(1))) void*)g,
      (__attribute__((address_space(3))) void*)l, 16, 0, 0);
}

// ---------------------------------------------------------------------------
// B=128, N=500. Stage A/B rows = 64000. Stage C: all 500 rows/batch direct
// (fps2 eliminated), padded to 512/batch -> M_C = 65536.
// ---------------------------------------------------------------------------
#define M_AB 64000
#define M_C 65536

#define OFF_ARENA_B 49152000u
#define OFF_IDX1 149815296u   // 128x500 int
#define OFF_FPSD 150071296u   // fps dist state
#define OFF_FPSI 150333440u   // fps fidx state
#define OFF_WB   150583296u   // bf16 weight arena (N,K padded), 1.57 MB

// ---------------------------------------------------------------------------
// FPS segment (unchanged, known-good): exact fp32, np.argmax tie-break.
// ---------------------------------------------------------------------------
template <int CTRL>
__device__ __forceinline__ float dppmaxf(float v) {
  int s = __builtin_amdgcn_update_dpp(0, __float_as_int(v), CTRL, 0xF, 0xF, true);
  return fmaxf(v, __uint_as_float((unsigned)s));
}

__device__ void fps_seg(const float4* cpt, int* out, const int* init1,
                        float* dstate, int* fstate, int b, int t0, int tcnt,
                        int lane) {
  float px[8], py[8], pz[8], dist[8];
  int base = lane * 8;
#pragma unroll
  for (int j = 0; j < 8; ++j) {
    int p = base + j;
    float4 c = cpt[p < 500 ? p : 0];
    px[j] = c.x; py[j] = c.y; pz[j] = c.z;
  }
  int fidx;
  if (t0 == 0) {
#pragma unroll
    for (int j = 0; j < 8; ++j) dist[j] = 1e10f;
    fidx = init1[b];
  } else {
#pragma unroll
    for (int j = 0; j < 8; ++j) dist[j] = dstate[(b * 64 + lane) * 8 + j];
    fidx = fstate[b];
  }

  int tend = t0 + tcnt;
  for (int t = t0; t < tend; ++t) {
    if (lane == 0) out[t] = fidx;
    if (t == 499) return;
    int lo = fidx >> 3, sl = fidx & 7;
    float cx, cy, cz;
    switch (sl) {
#define FPS_CASE(J) \
  case J: cx = rlf(px[J], lo); cy = rlf(py[J], lo); cz = rlf(pz[J], lo); break;
      FPS_CASE(0) FPS_CASE(1) FPS_CASE(2) FPS_CASE(3)
      FPS_CASE(4) FPS_CASE(5) FPS_CASE(6) FPS_CASE(7)
#undef FPS_CASE
      default: cx = cy = cz = 0.f; break;
    }
#pragma unroll
    for (int j = 0; j < 8; ++j) {
      float dx = __fsub_rn(px[j], cx);
      float dy = __fsub_rn(py[j], cy);
      float dz = __fsub_rn(pz[j], cz);
      float d = __fadd_rn(__fadd_rn(__fmul_rn(dx, dx), __fmul_rn(dy, dy)),
                          __fmul_rn(dz, dz));
      dist[j] = fminf(dist[j], d);
    }
    float m01 = fmaxf(dist[0], dist[1]), m23 = fmaxf(dist[2], dist[3]);
    float m45 = fmaxf(dist[4], dist[5]), m67 = fmaxf(dist[6], dist[7]);
    float lm = fmaxf(fmaxf(m01, m23), fmaxf(m45, m67));
    lm = dppmaxf<0x111>(lm);
    lm = dppmaxf<0x112>(lm);
    lm = dppmaxf<0x114>(lm);
    lm = dppmaxf<0x118>(lm);
    lm = dppmaxf<0x142>(lm);
    lm = dppmaxf<0x143>(lm);
    float mf = rlf(lm, 63);
    int sel = 8;
#pragma unroll
    for (int j = 7; j >= 0; --j) sel = (dist[j] == mf) ? j : sel;
    u64 mask = __ballot(sel != 8);
    int li = (int)__ffsll(mask) - 1;
    int sw = __builtin_amdgcn_readlane(sel, li);
    fidx = li * 8 + sw;
  }
#pragma unroll
  for (int j = 0; j < 8; ++j) dstate[(b * 64 + lane) * 8 + j] = dist[j];
  if (lane == 0) fstate[b] = fidx;
}

// ---------------------------------------------------------------------------
// MFMA GEMM body, m97-style: 128x128 tile, BK=64, global_load_lds staging,
// XOR-swizzled unpadded LDS [128][64]. 4 waves, each 64x64 (4x4 of 16x16x32).
// mode: 0 plain; 1 stage-B gather (b=r/500, idx row, concat x at lda..lda+2);
//       3 stage-C direct (b=r>>9, p=r&511; p>=500 rows garbage -> epilogue-
//       masked). act: 0 none, 1 relu, 2 relu + per-batch col max (512 r/b).
// A chunks with k0+64 <= lda use async fast path; tail (concat/zero, and the
// whole feat layer lda=4) uses VGPR fallback with the same swizzle.
// W arena is padded in K (64-mult) and N (128-mult): always fast path.
// ---------------------------------------------------------------------------
#define SMEM_BYTES (16384 * 2 + 1024)  // lA 16K + lB 16K + red 1K

__device__ __forceinline__ void gemm_body(
    const u16* __restrict__ A, int lda, const float* __restrict__ X,
    const int* __restrict__ idx, int mode, const u16* __restrict__ Wb,
    int ldw, const float* __restrict__ bias, u16* __restrict__ C, int ldc,
    int Kp, int N, int act, float* __restrict__ outf, int bx, int by,
    char* smem, int t) {
  u16* lA = (u16*)smem;             // [128][64] swizzled, unpadded
  u16* lB = (u16*)(smem + 16384);
  float* red = (float*)(smem + 32768);

  const int m0 = bx * 128, n0 = by * 128;
  const int w = t >> 6, lane = t & 63;
  const int mrow = lane & 15, quad = lane >> 4;
  const int wm = w >> 1, wn = w & 1;

  const int lrow8 = lane >> 3;      // 0..7
  const int sseg = (lane & 7) ^ lrow8;  // swizzled logical seg for this lane

  // fast-path row pointers: wave w stages rows [w*32, w*32+32), inst i covers
  // rows w*32+i*8+lrow8
  const u16* arow[4];
  const u16* wrow[4];
#pragma unroll
  for (int i = 0; i < 4; ++i) {
    int gr = m0 + w * 32 + i * 8 + lrow8;
    if (mode == 0) {
      arow[i] = A + (size_t)gr * lda;
    } else if (mode == 1) {
      int b = gr / 500;
      int p = gr - b * 500;
      int s = idx[b * 500 + p];
      arow[i] = A + ((size_t)b * 500 + s) * lda;
    } else {
      int b = gr >> 9;
      int p = gr & 511;
      arow[i] = A + ((size_t)b * 500 + (p < 500 ? p : 0)) * lda;
    }
    wrow[i] = Wb + (size_t)(n0 + w * 32 + i * 8 + lrow8) * ldw;
  }
  // fallback (tail-chunk) coords: thread t covers row t>>1, segs (t&1)*4..+4
  const int fr = t >> 1;
  const int fs0 = (t & 1) * 4;
  const u16* faptr;
  const float* fxptr = nullptr;
  bool fvalid = true;
  {
    int gr = m0 + fr;
    if (mode == 0) {
      faptr = A + (size_t)gr * lda;
    } else if (mode == 1) {
      int b = gr / 500;
      int p = gr - b * 500;
      int s = idx[b * 500 + p];
      size_t sr = (size_t)b * 500 + s;
      faptr = A + sr * lda;
      fxptr = X + sr * 3;
    } else {
      int b = gr >> 9;
      int p = gr & 511;
      fvalid = (p < 500);
      size_t sr = (size_t)b * 500 + (fvalid ? p : 0);
      faptr = A + sr * lda;
      fxptr = X + sr * 3;
    }
  }
  const int kfull = lda & ~63;

  f32x4 acc[4][4];
  const f32x4 fz = {0.f, 0.f, 0.f, 0.f};
#pragma unroll
  for (int i = 0; i < 4; ++i)
#pragma unroll
    for (int j = 0; j < 4; ++j) acc[i][j] = fz;

  for (int k0 = 0; k0 < Kp; k0 += 64) {
    __syncthreads();
    // W tile: always async fast path (arena padded)
#pragma unroll
    for (int i = 0; i < 4; ++i)
      gload16(wrow[i] + k0 + sseg * 8, lB + (w * 32 + i * 8) * 64);
    if (k0 < kfull) {
#pragma unroll
      for (int i = 0; i < 4; ++i)
        gload16(arow[i] + k0 + sseg * 8, lA + (w * 32 + i * 8) * 64);
    } else {
      // tail chunk: concat / zero fill, swizzle-aware ds_write
#pragma unroll
      for (int s4 = 0; s4 < 4; ++s4) {
        int seg = fs0 + s4;
        us8 v = {0, 0, 0, 0, 0, 0, 0, 0};
        if (fvalid) {
          int kb = k0 + seg * 8;
#pragma unroll
          for (int j = 0; j < 8; ++j) {
            int k = kb + j;
            u16 vv = 0;
            if (k < lda) vv = faptr[k];
            else if (mode != 0 && k < lda + 3) vv = f2bf(fxptr[k - lda]);
            v[j] = vv;
          }
        }
        *(us8*)(lA + fr * 64 + (seg ^ (fr & 7)) * 8) = v;
      }
    }
    __syncthreads();

#pragma unroll
    for (int kh = 0; kh < 2; ++kh) {
      bf16x8 af[4], bfv[4];
#pragma unroll
      for (int mi = 0; mi < 4; ++mi) {
        int r = wm * 64 + mi * 16 + mrow;
        af[mi] = *(const bf16x8*)(lA + r * 64 + ((kh * 4 + quad) ^ (r & 7)) * 8);
      }
#pragma unroll
      for (int ni = 0; ni < 4; ++ni) {
        int r = wn * 64 + ni * 16 + mrow;
        bfv[ni] = *(const bf16x8*)(lB + r * 64 + ((kh * 4 + quad) ^ (r & 7)) * 8);
      }
#pragma unroll
      for (int mi = 0; mi < 4; ++mi)
#pragma unroll
        for (int ni = 0; ni < 4; ++ni)
          acc[mi][ni] = __builtin_amdgcn_mfma_f32_16x16x32_bf16(
              af[mi], bfv[ni], acc[mi][ni], 0, 0, 0);
    }
  }

  if (act < 2) {
#pragma unroll
    for (int ni = 0; ni < 4; ++ni) {
      int col = n0 + wn * 64 + ni * 16 + mrow;
      if (col >= N) continue;
      float bv = bias[col];
#pragma unroll
      for (int mi = 0; mi < 4; ++mi)
#pragma unroll
        for (int r = 0; r < 4; ++r) {
          int grow = m0 + wm * 64 + mi * 16 + quad * 4 + r;
          float v = acc[mi][ni][r] + bv;
          if (act == 1) v = fmaxf(v, 0.f);
          C[(size_t)grow * ldc + col] = f2bf(v);
        }
    }
  } else {
#pragma unroll
    for (int ni = 0; ni < 4; ++ni) {
      int col = n0 + wn * 64 + ni * 16 + mrow;
      float bv = (col < N) ? bias[col] : 0.f;
      float mx = 0.f;
#pragma unroll
      for (int mi = 0; mi < 4; ++mi)
#pragma unroll
        for (int r = 0; r < 4; ++r) {
          int grow = m0 + wm * 64 + mi * 16 + quad * 4 + r;
          float v = fmaxf(acc[mi][ni][r] + bv, 0.f);
          if ((grow & 511) < 500) mx = fmaxf(mx, v);
        }
      mx = fmaxf(mx, __shfl_xor(mx, 16, 64));
      mx = fmaxf(mx, __shfl_xor(mx, 32, 64));
      if (quad == 0) red[wm * 128 + wn * 64 + ni * 16 + mrow] = mx;
    }
    __syncthreads();
    if (t < 128) {
      int col = n0 + t;
      if (col < N) {
        float m = fmaxf(red[t], red[128 + t]);
        int b = m0 >> 9;
        atomicMax((unsigned*)&outf[b * 512 + col], __float_as_uint(m));
      }
    }
  }
}

__global__ __launch_bounds__(256) void gemm_mfma(
    const u16* __restrict__ A, int lda, const float* __restrict__ X,
    const int* __restrict__ idx, int mode, const u16* __restrict__ Wb,
    int ldw, const float* __restrict__ bias, u16* __restrict__ C, int ldc,
    int Kp, int N, int act, float* __restrict__ outf) {
  __shared__ __align__(16) char smem[SMEM_BYTES];
  gemm_body(A, lda, X, idx, mode, Wb, ldw, bias, C, ldc, Kp, N, act, outf,
            blockIdx.x, blockIdx.y, smem, threadIdx.x);
}

// GEMM + FPS segment fused; FPS blocks FIRST (0..127) so they start at t=0
__global__ __launch_bounds__(256) void gemm_fps(
    const u16* __restrict__ A, int lda, const u16* __restrict__ Wb, int ldw,
    const float* __restrict__ bias, u16* __restrict__ C, int ldc, int Kp,
    int N, int act, int gx, const float* __restrict__ x,
    const int* __restrict__ init1, int* __restrict__ idx1,
    float* __restrict__ dstate, int* __restrict__ fstate, int t0, int tcnt) {
  __shared__ __align__(16) char smem[SMEM_BYTES];
  int bid = blockIdx.x;
  int t = threadIdx.x;
  if (bid < 128) {
    int b = bid;
    float4* cpt = (float4*)smem;
    const float* xb = x + (size_t)b * 1500;
    for (int p = t; p < 500; p += 256)
      cpt[p] = make_float4(xb[p * 3], xb[p * 3 + 1], xb[p * 3 + 2], 0.f);
    __syncthreads();
    if (t < 64)
      fps_seg(cpt, idx1 + b * 500, init1, dstate, fstate, b, t0, tcnt, t);
  } else {
    int g = bid - 128;
    int by = g / gx, bx = g - by * gx;
    gemm_body(A, lda, nullptr, nullptr, 0, Wb, ldw, bias, C, ldc, Kp, N, act,
              nullptr, bx, by, smem, t);
  }
}

// ---------------------------------------------------------------------------
// prep (+ FPS segment 0): weight converts (K,N zero-padded) + zero + feat
// ---------------------------------------------------------------------------
struct PrepArgs {
  const float* wsrc[8];
  u16* wdst[8];
  int wN[8], wK[8], wKp[8];
  int wstart[9];
};

__global__ __launch_bounds__(256) void prep_kernel(
    PrepArgs pa, const float* __restrict__ x, const float* __restrict__ cW,
    const float* __restrict__ cb, u16* __restrict__ feat,
    float* __restrict__ outf, const int* __restrict__ init1,
    int* __restrict__ idx1, float* __restrict__ dstate,
    int* __restrict__ fstate) {
  __shared__ float4 cpt[512];
  int bid = blockIdx.x;
  int t = threadIdx.x;
  if (bid < 128) {
    int b = bid;
    const float* xb = x + (size_t)b * 1500;
    for (int p = t; p < 500; p += 256)
      cpt[p] = make_float4(xb[p * 3], xb[p * 3 + 1], xb[p * 3 + 2], 0.f);
    __syncthreads();
    if (t < 64) fps_seg(cpt, idx1 + b * 500, init1, dstate, fstate, b, 0, 125, t);
    return;
  }
  int i = (bid - 128) * 256 + t;
  int S = pa.wstart[8];
  if (i < S) {
    int w = 0;
#pragma unroll
    for (int j = 1; j < 8; ++j)
      if (i >= pa.wstart[j]) w = j;
    int local = i - pa.wstart[w];
    int Kp = pa.wKp[w];
    int n = local / Kp, k = local - n * Kp;
    pa.wdst[w][local] =
        (n < pa.wN[w] && k < pa.wK[w]) ? f2bf(pa.wsrc[w][n * pa.wK[w] + k]) : (u16)0;
  } else if (i < S + 65536) {
    outf[i - S] = 0.f;
  } else {
    int r = i - S - 65536;
    if (r < M_AB) {
      float x0 = x[r * 3], x1 = x[r * 3 + 1], x2 = x[r * 3 + 2];
      float z = x0 * cW[0] + x1 * cW[1] + x2 * cW[2] + cb[0];
      float conf = 1.0f / (1.0f + expf(-z));
      feat[r * 4 + 0] = f2bf(conf);
      feat[r * 4 + 1] = f2bf(x0);
      feat[r * 4 + 2] = f2bf(x1);
      feat[r * 4 + 3] = f2bf(x2);
    }
  }
}

// ---------------------------------------------------------------------------
extern "C" void kernel_launch(void* const* d_in, const int* in_sizes, int n_in,
                              void* d_out, int out_size, void* d_ws,
                              size_t ws_size, hipStream_t stream) {
  const float* x      = (const float*)d_in[0];
  const float* conf_W = (const float*)d_in[1];
  const float* conf_b = (const float*)d_in[2];
  const float* w1     = (const float*)d_in[3];
  const float* b1     = (const float*)d_in[4];
  const float* w2     = (const float*)d_in[5];
  const float* b2     = (const float*)d_in[6];
  const float* pc1_W  = (const float*)d_in[7];
  const float* pc1_b  = (const float*)d_in[8];
  const float* w3     = (const float*)d_in[9];
  const float* b3     = (const float*)d_in[10];
  const float* w4     = (const float*)d_in[11];
  const float* b4     = (const float*)d_in[12];
  const float* pc2_W  = (const float*)d_in[13];
  const float* pc2_b  = (const float*)d_in[14];
  const float* w5     = (const float*)d_in[15];
  const float* b5     = (const float*)d_in[16];
  const float* w6     = (const float*)d_in[17];
  const float* b6     = (const float*)d_in[18];
  const int* init1    = (const int*)d_in[20];

  char* ws = (char*)d_ws;
  u16* feat = (u16*)(ws + 0);
  u16* l2b  = (u16*)(ws + 0);
  u16* l4b  = (u16*)(ws + 0);
  u16* l6b  = (u16*)(ws + 0);
  u16* l1b  = (u16*)(ws + OFF_ARENA_B);
  u16* l3b  = (u16*)(ws + OFF_ARENA_B);
  u16* l5b  = (u16*)(ws + OFF_ARENA_B);
  u16* l7b  = (u16*)(ws + OFF_ARENA_B);
  int* idx1 = (int*)(ws + OFF_IDX1);
  float* dstate = (float*)(ws + OFF_FPSD);
  int* fstate   = (int*)(ws + OFF_FPSI);
  u16* wb   = (u16*)(ws + OFF_WB);
  float* outf = (float*)d_out;  // 128x512 fp32, accumulated via atomicMax

  // weight arena: N padded to 128-mult (zero rows), K padded to 64-mult
  PrepArgs pa;
  const float* srcs[8] = {w1, w2, pc1_W, w3, w4, pc2_W, w5, w6};
  int Ns[8]  = {64, 256, 256, 256, 384, 384, 384, 512};   // true N
  int Nps[8] = {128, 256, 256, 256, 384, 384, 384, 512};  // padded N
  int Ks[8]  = {4, 64, 256, 259, 256, 384, 387, 384};     // true K
  int Kps[8] = {64, 64, 256, 320, 256, 384, 448, 384};    // padded K
  u16* WBp[8];
  int cum = 0;
  for (int i = 0; i < 8; ++i) {
    pa.wsrc[i] = srcs[i];
    pa.wdst[i] = WBp[i] = wb + cum;
    pa.wN[i] = Ns[i];
    pa.wK[i] = Ks[i];
    pa.wKp[i] = Kps[i];
    pa.wstart[i] = cum;
    cum += Nps[i] * Kps[i];
  }
  pa.wstart[8] = cum;  // 786,432 elems
  int total = cum + 65536 + M_AB;

  // prep + FPS seg0 (iters 0..124)
  prep_kernel<<<128 + (total + 255) / 256, 256, 0, stream>>>(
      pa, x, conf_W, conf_b, feat, outf, init1, idx1, dstate, fstate);
  // stage A + FPS segs 1..3 (FPS blocks first in each kernel)
  gemm_fps<<<128 + 500, 256, 0, stream>>>(feat, 4, WBp[0], 64, b1, l1b, 64,
      64, 64, 1, 500, x, init1, idx1, dstate, fstate, 125, 125);
  gemm_fps<<<128 + 1000, 256, 0, stream>>>(l1b, 64, WBp[1], 64, b2, l2b, 256,
      64, 256, 1, 500, x, init1, idx1, dstate, fstate, 250, 125);
  gemm_fps<<<128 + 1000, 256, 0, stream>>>(l2b, 256, WBp[2], 256, pc1_b, l3b,
      256, 256, 256, 0, 500, x, init1, idx1, dstate, fstate, 375, 125);
  // stage B (gather fused, mode 1)
  gemm_mfma<<<dim3(500, 2), 256, 0, stream>>>(l3b, 256, x, idx1, 1,
      WBp[3], 320, b3, l4b, 256, 320, 256, 1, nullptr);
  gemm_mfma<<<dim3(500, 3), 256, 0, stream>>>(l4b, 256, nullptr, nullptr, 0,
      WBp[4], 256, b4, l5b, 384, 256, 384, 1, nullptr);
  gemm_mfma<<<dim3(500, 3), 256, 0, stream>>>(l5b, 384, nullptr, nullptr, 0,
      WBp[5], 384, pc2_b, l6b, 384, 384, 384, 0, nullptr);
  // stage C (direct concat over all 500 rows/batch, pad 512)
  gemm_mfma<<<dim3(512, 3), 256, 0, stream>>>(l6b, 384, x, nullptr, 3,
      WBp[6], 448, b5, l7b, 384, 448, 384, 1, nullptr);
  gemm_mfma<<<dim3(512, 4), 256, 0, stream>>>(l7b, 384, nullptr, nullptr, 0,
      WBp[7], 384, b6, nullptr, 0, 384, 512, 2, outf);
}

// Round 10
// 400.009 us; speedup vs baseline: 14.0612x; 1.1826x over previous
//
#include <hip/hip_runtime.h>

typedef unsigned short u16;
typedef short bf16x8 __attribute__((ext_vector_type(8)));   // 8 bf16 (4 VGPRs)
typedef float f32x4 __attribute__((ext_vector_type(4)));
typedef unsigned short us8 __attribute__((ext_vector_type(8)));
typedef unsigned long long u64;

__device__ __forceinline__ float bf2f(u16 u) {
  return __uint_as_float(((unsigned)u) << 16);
}
__device__ __forceinline__ u16 f2bf(float f) {
  unsigned u = __float_as_uint(f);
  u += 0x7fffu + ((u >> 16) & 1u);  // RNE (no NaNs in this workload)
  return (u16)(u >> 16);
}
__device__ __forceinline__ float rlf(float v, int l) {
  return __uint_as_float((unsigned)__builtin_amdgcn_readlane(__float_as_int(v), l));
}
// async global(16B/lane) -> LDS(wave-uniform base + lane*16) [m97-verified]
__device__ __forceinline__ void gload16(const u16* g, u16* l) {
  __builtin_amdgcn_global_load_lds(
      (const __attribute__((address_space(1))) void*)g,
      (__attribute__((address_space(3))) void*)l, 16, 0, 0);
}

// ---------------------------------------------------------------------------
// B=128, N=500. Stages A/B: 64000 unpermuted rows (stage B needs no idx1 —
// permutation deferred to stage C via l6u[idx1[p]] gather). Stage C padded
// to 512 rows/batch -> 65536.
// ---------------------------------------------------------------------------
#define M_AB 64000
#define M_C 65536

#define OFF_ARENA_B 49152000u
#define OFF_IDX1 149815296u   // 128x500 int
#define OFF_FPSD 150071296u   // fps dist state (256 KB)
#define OFF_FPSI 150333440u   // fps fidx state
#define OFF_WB   150583296u   // bf16 weight arena (N,K padded)

// ---------------------------------------------------------------------------
// FPS segment: iters [t0,t0+tcnt). Exact fp32 (_rn, np sum order), np.argmax
// first-max tie-break. Branch-free centroid: tie-scan selects slot AND coords
// via cndmask; winner lane's coords broadcast by readlane (SGPR index from
// ballot/ffs). State (dist,fidx) persists in ws across segments.
// ---------------------------------------------------------------------------
template <int CTRL>
__device__ __forceinline__ float dppmaxf(float v) {
  int s = __builtin_amdgcn_update_dpp(0, __float_as_int(v), CTRL, 0xF, 0xF, true);
  return fmaxf(v, __uint_as_float((unsigned)s));
}

__device__ void fps_seg(const float4* cpt, int* out, const int* init1,
                        float* dstate, int* fstate, int b, int t0, int tcnt,
                        int lane) {
  float px[8], py[8], pz[8], dist[8];
  int base = lane * 8;
#pragma unroll
  for (int j = 0; j < 8; ++j) {
    int p = base + j;
    float4 c = cpt[p < 500 ? p : 0];  // invalid slots duplicate point 0
    px[j] = c.x; py[j] = c.y; pz[j] = c.z;
  }
  int fidx;
  if (t0 == 0) {
#pragma unroll
    for (int j = 0; j < 8; ++j) dist[j] = 1e10f;
    fidx = init1[b];
  } else {
#pragma unroll
    for (int j = 0; j < 8; ++j) dist[j] = dstate[(b * 64 + lane) * 8 + j];
    fidx = fstate[b];
  }
  float4 c0 = cpt[fidx];  // centroid for first update (uniform LDS read)
  float cx = c0.x, cy = c0.y, cz = c0.z;

  int tend = t0 + tcnt;
  for (int t = t0; t < tend; ++t) {
    if (lane == 0) out[t] = fidx;
    if (t == 499) return;
#pragma unroll
    for (int j = 0; j < 8; ++j) {
      float dx = __fsub_rn(px[j], cx);
      float dy = __fsub_rn(py[j], cy);
      float dz = __fsub_rn(pz[j], cz);
      float d = __fadd_rn(__fadd_rn(__fmul_rn(dx, dx), __fmul_rn(dy, dy)),
                          __fmul_rn(dz, dz));
      dist[j] = fminf(dist[j], d);
    }
    float m01 = fmaxf(dist[0], dist[1]), m23 = fmaxf(dist[2], dist[3]);
    float m45 = fmaxf(dist[4], dist[5]), m67 = fmaxf(dist[6], dist[7]);
    float lm = fmaxf(fmaxf(m01, m23), fmaxf(m45, m67));
    lm = dppmaxf<0x111>(lm);
    lm = dppmaxf<0x112>(lm);
    lm = dppmaxf<0x114>(lm);
    lm = dppmaxf<0x118>(lm);
    lm = dppmaxf<0x142>(lm);
    lm = dppmaxf<0x143>(lm);
    float mf = rlf(lm, 63);
    // tie-scan: smallest slot with dist==max, carrying its coords (cndmask)
    int sel = 8;
    float sx = 0.f, sy = 0.f, sz = 0.f;
#pragma unroll
    for (int j = 7; j >= 0; --j) {
      bool hit = (dist[j] == mf);
      sel = hit ? j : sel;
      sx = hit ? px[j] : sx;
      sy = hit ? py[j] : sy;
      sz = hit ? pz[j] : sz;
    }
    u64 mask = __ballot(sel != 8);
    int li = (int)__ffsll(mask) - 1;  // smallest lane = smallest point range
    fidx = li * 8 + __builtin_amdgcn_readlane(sel, li);
    cx = rlf(sx, li);
    cy = rlf(sy, li);
    cz = rlf(sz, li);
  }
#pragma unroll
  for (int j = 0; j < 8; ++j) dstate[(b * 64 + lane) * 8 + j] = dist[j];
  if (lane == 0) fstate[b] = fidx;
}

// ---------------------------------------------------------------------------
// MFMA GEMM body: 128x128 tile, BK=64, global_load_lds staging, XOR-swizzled
// unpadded LDS [128][64]. 4 waves, each 64x64 (4x4 of 16x16x32).
// mode 0: plain A rows.
// mode 2: direct concat (row r: A[r] cols [0,lda), x[r] at lda..lda+2).
// mode 4: stage-C permuted gather (b=r>>9, p=r&511 clamped to <500;
//         A row b*500+idx1[b*500+p], concat x[b*500+p]).
// act: 0 none, 1 relu, 2 relu + per-batch col max -> atomicMax (512 r/b,
//      rows (r&511)>=500 masked).
// ---------------------------------------------------------------------------
#define SMEM_BYTES (16384 * 2 + 1024)

__device__ __forceinline__ void gemm_body(
    const u16* __restrict__ A, int lda, const float* __restrict__ X,
    const int* __restrict__ idx, int mode, const u16* __restrict__ Wb,
    int ldw, const float* __restrict__ bias, u16* __restrict__ C, int ldc,
    int Kp, int N, int act, float* __restrict__ outf, int bx, int by,
    char* smem, int t) {
  u16* lA = (u16*)smem;
  u16* lB = (u16*)(smem + 16384);
  float* red = (float*)(smem + 32768);

  const int m0 = bx * 128, n0 = by * 128;
  const int w = t >> 6, lane = t & 63;
  const int mrow = lane & 15, quad = lane >> 4;
  const int wm = w >> 1, wn = w & 1;

  const int lrow8 = lane >> 3;
  const int sseg = (lane & 7) ^ lrow8;

  const u16* arow[4];
  const u16* wrow[4];
#pragma unroll
  for (int i = 0; i < 4; ++i) {
    int gr = m0 + w * 32 + i * 8 + lrow8;
    if (mode == 4) {
      int b = gr >> 9;
      int p = gr & 511;
      int pe = (p < 500) ? p : 0;
      int s = idx[b * 500 + pe];
      arow[i] = A + ((size_t)b * 500 + s) * lda;
    } else {
      arow[i] = A + (size_t)gr * lda;
    }
    wrow[i] = Wb + (size_t)(n0 + w * 32 + i * 8 + lrow8) * ldw;
  }
  // fallback (tail-chunk) coords: thread t covers row t>>1, segs (t&1)*4..+4
  const int fr = t >> 1;
  const int fs0 = (t & 1) * 4;
  const u16* faptr;
  const float* fxptr = nullptr;
  {
    int gr = m0 + fr;
    if (mode == 4) {
      int b = gr >> 9;
      int p = gr & 511;
      int pe = (p < 500) ? p : 0;
      int s = idx[b * 500 + pe];
      faptr = A + ((size_t)b * 500 + s) * lda;
      fxptr = X + ((size_t)b * 500 + pe) * 3;
    } else {
      faptr = A + (size_t)gr * lda;
      if (mode == 2) fxptr = X + (size_t)gr * 3;
    }
  }
  const int kfull = lda & ~63;

  f32x4 acc[4][4];
  const f32x4 fz = {0.f, 0.f, 0.f, 0.f};
#pragma unroll
  for (int i = 0; i < 4; ++i)
#pragma unroll
    for (int j = 0; j < 4; ++j) acc[i][j] = fz;

  for (int k0 = 0; k0 < Kp; k0 += 64) {
    __syncthreads();
#pragma unroll
    for (int i = 0; i < 4; ++i)
      gload16(wrow[i] + k0 + sseg * 8, lB + (w * 32 + i * 8) * 64);
    if (k0 < kfull) {
#pragma unroll
      for (int i = 0; i < 4; ++i)
        gload16(arow[i] + k0 + sseg * 8, lA + (w * 32 + i * 8) * 64);
    } else {
#pragma unroll
      for (int s4 = 0; s4 < 4; ++s4) {
        int seg = fs0 + s4;
        us8 v = {0, 0, 0, 0, 0, 0, 0, 0};
        int kb = k0 + seg * 8;
#pragma unroll
        for (int j = 0; j < 8; ++j) {
          int k = kb + j;
          u16 vv = 0;
          if (k < lda) vv = faptr[k];
          else if (mode != 0 && k < lda + 3) vv = f2bf(fxptr[k - lda]);
          v[j] = vv;
        }
        *(us8*)(lA + fr * 64 + (seg ^ (fr & 7)) * 8) = v;
      }
    }
    __syncthreads();

#pragma unroll
    for (int kh = 0; kh < 2; ++kh) {
      bf16x8 af[4], bfv[4];
#pragma unroll
      for (int mi = 0; mi < 4; ++mi) {
        int r = wm * 64 + mi * 16 + mrow;
        af[mi] = *(const bf16x8*)(lA + r * 64 + ((kh * 4 + quad) ^ (r & 7)) * 8);
      }
#pragma unroll
      for (int ni = 0; ni < 4; ++ni) {
        int r = wn * 64 + ni * 16 + mrow;
        bfv[ni] = *(const bf16x8*)(lB + r * 64 + ((kh * 4 + quad) ^ (r & 7)) * 8);
      }
#pragma unroll
      for (int mi = 0; mi < 4; ++mi)
#pragma unroll
        for (int ni = 0; ni < 4; ++ni)
          acc[mi][ni] = __builtin_amdgcn_mfma_f32_16x16x32_bf16(
              af[mi], bfv[ni], acc[mi][ni], 0, 0, 0);
    }
  }

  if (act < 2) {
#pragma unroll
    for (int ni = 0; ni < 4; ++ni) {
      int col = n0 + wn * 64 + ni * 16 + mrow;
      if (col >= N) continue;
      float bv = bias[col];
#pragma unroll
      for (int mi = 0; mi < 4; ++mi)
#pragma unroll
        for (int r = 0; r < 4; ++r) {
          int grow = m0 + wm * 64 + mi * 16 + quad * 4 + r;
          float v = acc[mi][ni][r] + bv;
          if (act == 1) v = fmaxf(v, 0.f);
          C[(size_t)grow * ldc + col] = f2bf(v);
        }
    }
  } else {
#pragma unroll
    for (int ni = 0; ni < 4; ++ni) {
      int col = n0 + wn * 64 + ni * 16 + mrow;
      float bv = (col < N) ? bias[col] : 0.f;
      float mx = 0.f;
#pragma unroll
      for (int mi = 0; mi < 4; ++mi)
#pragma unroll
        for (int r = 0; r < 4; ++r) {
          int grow = m0 + wm * 64 + mi * 16 + quad * 4 + r;
          float v = fmaxf(acc[mi][ni][r] + bv, 0.f);
          if ((grow & 511) < 500) mx = fmaxf(mx, v);
        }
      mx = fmaxf(mx, __shfl_xor(mx, 16, 64));
      mx = fmaxf(mx, __shfl_xor(mx, 32, 64));
      if (quad == 0) red[wm * 128 + wn * 64 + ni * 16 + mrow] = mx;
    }
    __syncthreads();
    if (t < 128) {
      int col = n0 + t;
      if (col < N) {
        float m = fmaxf(red[t], red[128 + t]);
        int b = m0 >> 9;
        atomicMax((unsigned*)&outf[b * 512 + col], __float_as_uint(m));
      }
    }
  }
}

__global__ __launch_bounds__(256) void gemm_mfma(
    const u16* __restrict__ A, int lda, const float* __restrict__ X,
    const int* __restrict__ idx, int mode, const u16* __restrict__ Wb,
    int ldw, const float* __restrict__ bias, u16* __restrict__ C, int ldc,
    int Kp, int N, int act, float* __restrict__ outf) {
  __shared__ __align__(16) char smem[SMEM_BYTES];
  gemm_body(A, lda, X, idx, mode, Wb, ldw, bias, C, ldc, Kp, N, act, outf,
            blockIdx.x, blockIdx.y, smem, threadIdx.x);
}

// GEMM + FPS segment fused; FPS blocks FIRST (0..127) so they start at t=0
__global__ __launch_bounds__(256) void gemm_fps(
    const u16* __restrict__ A, int lda, const float* __restrict__ X,
    int mode, const u16* __restrict__ Wb, int ldw,
    const float* __restrict__ bias, u16* __restrict__ C, int ldc, int Kp,
    int N, int act, int gx, const float* __restrict__ x,
    const int* __restrict__ init1, int* __restrict__ idx1,
    float* __restrict__ dstate, int* __restrict__ fstate, int t0, int tcnt) {
  __shared__ __align__(16) char smem[SMEM_BYTES];
  int bid = blockIdx.x;
  int t = threadIdx.x;
  if (bid < 128) {
    int b = bid;
    float4* cpt = (float4*)smem;
    const float* xb = x + (size_t)b * 1500;
    for (int p = t; p < 500; p += 256)
      cpt[p] = make_float4(xb[p * 3], xb[p * 3 + 1], xb[p * 3 + 2], 0.f);
    __syncthreads();
    if (t < 64)
      fps_seg(cpt, idx1 + b * 500, init1, dstate, fstate, b, t0, tcnt, t);
  } else {
    int g = bid - 128;
    int by = g / gx, bx = g - by * gx;
    gemm_body(A, lda, X, nullptr, mode, Wb, ldw, bias, C, ldc, Kp, N, act,
              nullptr, bx, by, smem, t);
  }
}

// ---------------------------------------------------------------------------
// prep (+ FPS segment 0): weight converts (K,N zero-padded) + zero + feat
// ---------------------------------------------------------------------------
struct PrepArgs {
  const float* wsrc[8];
  u16* wdst[8];
  int wN[8], wK[8], wKp[8];
  int wstart[9];
};

__global__ __launch_bounds__(256) void prep_kernel(
    PrepArgs pa, const float* __restrict__ x, const float* __restrict__ cW,
    const float* __restrict__ cb, u16* __restrict__ feat,
    float* __restrict__ outf, const int* __restrict__ init1,
    int* __restrict__ idx1, float* __restrict__ dstate,
    int* __restrict__ fstate, int tcnt) {
  __shared__ float4 cpt[512];
  int bid = blockIdx.x;
  int t = threadIdx.x;
  if (bid < 128) {
    int b = bid;
    const float* xb = x + (size_t)b * 1500;
    for (int p = t; p < 500; p += 256)
      cpt[p] = make_float4(xb[p * 3], xb[p * 3 + 1], xb[p * 3 + 2], 0.f);
    __syncthreads();
    if (t < 64) fps_seg(cpt, idx1 + b * 500, init1, dstate, fstate, b, 0, tcnt, t);
    return;
  }
  int i = (bid - 128) * 256 + t;
  int S = pa.wstart[8];
  if (i < S) {
    int w = 0;
#pragma unroll
    for (int j = 1; j < 8; ++j)
      if (i >= pa.wstart[j]) w = j;
    int local = i - pa.wstart[w];
    int Kp = pa.wKp[w];
    int n = local / Kp, k = local - n * Kp;
    pa.wdst[w][local] =
        (n < pa.wN[w] && k < pa.wK[w]) ? f2bf(pa.wsrc[w][n * pa.wK[w] + k]) : (u16)0;
  } else if (i < S + 65536) {
    outf[i - S] = 0.f;
  } else {
    int r = i - S - 65536;
    if (r < M_AB) {
      float x0 = x[r * 3], x1 = x[r * 3 + 1], x2 = x[r * 3 + 2];
      float z = x0 * cW[0] + x1 * cW[1] + x2 * cW[2] + cb[0];
      float conf = 1.0f / (1.0f + expf(-z));
      feat[r * 4 + 0] = f2bf(conf);
      feat[r * 4 + 1] = f2bf(x0);
      feat[r * 4 + 2] = f2bf(x1);
      feat[r * 4 + 3] = f2bf(x2);
    }
  }
}

// ---------------------------------------------------------------------------
extern "C" void kernel_launch(void* const* d_in, const int* in_sizes, int n_in,
                              void* d_out, int out_size, void* d_ws,
                              size_t ws_size, hipStream_t stream) {
  const float* x      = (const float*)d_in[0];
  const float* conf_W = (const float*)d_in[1];
  const float* conf_b = (const float*)d_in[2];
  const float* w1     = (const float*)d_in[3];
  const float* b1     = (const float*)d_in[4];
  const float* w2     = (const float*)d_in[5];
  const float* b2     = (const float*)d_in[6];
  const float* pc1_W  = (const float*)d_in[7];
  const float* pc1_b  = (const float*)d_in[8];
  const float* w3     = (const float*)d_in[9];
  const float* b3     = (const float*)d_in[10];
  const float* w4     = (const float*)d_in[11];
  const float* b4     = (const float*)d_in[12];
  const float* pc2_W  = (const float*)d_in[13];
  const float* pc2_b  = (const float*)d_in[14];
  const float* w5     = (const float*)d_in[15];
  const float* b5     = (const float*)d_in[16];
  const float* w6     = (const float*)d_in[17];
  const float* b6     = (const float*)d_in[18];
  const int* init1    = (const int*)d_in[20];

  char* ws = (char*)d_ws;
  u16* feat = (u16*)(ws + 0);
  u16* l2b  = (u16*)(ws + 0);
  u16* l4b  = (u16*)(ws + 0);
  u16* l6u  = (u16*)(ws + 0);
  u16* l1b  = (u16*)(ws + OFF_ARENA_B);
  u16* l3b  = (u16*)(ws + OFF_ARENA_B);
  u16* l5b  = (u16*)(ws + OFF_ARENA_B);
  u16* l7b  = (u16*)(ws + OFF_ARENA_B);
  int* idx1 = (int*)(ws + OFF_IDX1);
  float* dstate = (float*)(ws + OFF_FPSD);
  int* fstate   = (int*)(ws + OFF_FPSI);
  u16* wb   = (u16*)(ws + OFF_WB);
  float* outf = (float*)d_out;  // 128x512 fp32, accumulated via atomicMax

  PrepArgs pa;
  const float* srcs[8] = {w1, w2, pc1_W, w3, w4, pc2_W, w5, w6};
  int Ns[8]  = {64, 256, 256, 256, 384, 384, 384, 512};
  int Nps[8] = {128, 256, 256, 256, 384, 384, 384, 512};
  int Ks[8]  = {4, 64, 256, 259, 256, 384, 387, 384};
  int Kps[8] = {64, 64, 256, 320, 256, 384, 448, 384};
  u16* WBp[8];
  int cum = 0;
  for (int i = 0; i < 8; ++i) {
    pa.wsrc[i] = srcs[i];
    pa.wdst[i] = WBp[i] = wb + cum;
    pa.wN[i] = Ns[i];
    pa.wK[i] = Ks[i];
    pa.wKp[i] = Kps[i];
    pa.wstart[i] = cum;
    cum += Nps[i] * Kps[i];
  }
  pa.wstart[8] = cum;
  int total = cum + 65536 + M_AB;

  // FPS split over 7 dispatches: 60,40,50,70,85,90,105 iters (sum 500)
  prep_kernel<<<128 + (total + 255) / 256, 256, 0, stream>>>(
      pa, x, conf_W, conf_b, feat, outf, init1, idx1, dstate, fstate, 60);
  // stage A (pure GEMMs + FPS segments; FPS blocks first)
  gemm_fps<<<128 + 500, 256, 0, stream>>>(feat, 4, nullptr, 0, WBp[0], 64,
      b1, l1b, 64, 64, 64, 1, 500, x, init1, idx1, dstate, fstate, 60, 40);
  gemm_fps<<<128 + 1000, 256, 0, stream>>>(l1b, 64, nullptr, 0, WBp[1], 64,
      b2, l2b, 256, 64, 256, 1, 500, x, init1, idx1, dstate, fstate, 100, 50);
  gemm_fps<<<128 + 1000, 256, 0, stream>>>(l2b, 256, nullptr, 0, WBp[2], 256,
      pc1_b, l3b, 256, 256, 256, 0, 500, x, init1, idx1, dstate, fstate, 150, 70);
  // stage B — unpermuted rows (no idx1 dependency!)
  gemm_fps<<<128 + 1000, 256, 0, stream>>>(l3b, 256, x, 2, WBp[3], 320,
      b3, l4b, 256, 320, 256, 1, 500, x, init1, idx1, dstate, fstate, 220, 85);
  gemm_fps<<<128 + 1500, 256, 0, stream>>>(l4b, 256, nullptr, 0, WBp[4], 256,
      b4, l5b, 384, 256, 384, 1, 500, x, init1, idx1, dstate, fstate, 305, 90);
  gemm_fps<<<128 + 1500, 256, 0, stream>>>(l5b, 384, nullptr, 0, WBp[5], 384,
      pc2_b, l6u, 384, 384, 384, 0, 500, x, init1, idx1, dstate, fstate, 395, 105);
  // stage C — permutation applied here (mode 4), then final layer + max
  gemm_mfma<<<dim3(512, 3), 256, 0, stream>>>(l6u, 384, x, idx1, 4,
      WBp[6], 448, b5, l7b, 384, 448, 384, 1, nullptr);
  gemm_mfma<<<dim3(512, 4), 256, 0, stream>>>(l7b, 384, nullptr, nullptr, 0,
      WBp[7], 384, b6, nullptr, 0, 384, 512, 2, outf);
}